// Round 13
// baseline (780.104 us; speedup 1.0000x reference)
//
#include <hip/hip_runtime.h>
#include <cstdint>
#include <cstddef>

// Sizes (fixed by the problem)
#define NQPAD 1664        // padded N dim for GEMM grids (13 * 128)
#define QLD 1544          // q row stride (16B-aligned, 1540 valid)
#define KC 192            // K/8 chunks for the 1536-K tiled GEMM
#define NPAIR 2016        // unordered pairs per batch (64*63/2)
#define PROW 2048         // padded pair-rows per batch

typedef __bf16 bf16x8 __attribute__((ext_vector_type(8)));
typedef float  f32x4  __attribute__((ext_vector_type(4)));
typedef unsigned short ushort_t;

__device__ __forceinline__ unsigned short f2bf(float f) {
  union { float f; unsigned u; } v; v.f = f;
  unsigned r = v.u + 0x7fffu + ((v.u >> 16) & 1u);
  return (unsigned short)(r >> 16);
}
__device__ __forceinline__ float bf2f(unsigned short h) {
  union { unsigned u; float f; } v; v.u = ((unsigned)h) << 16;
  return v.f;
}
// fast elu: v_exp_f32 path (~5 instr). rel err ~1e-7.
__device__ __forceinline__ float elu_f(float x) {
  return x > 0.f ? x : __expf(x) - 1.f;
}

// async global -> LDS, 16B per lane; lds base wave-uniform (HW: base + lane*16)
__device__ __forceinline__ void cp16_lds(const ushort_t* g, ushort_t* l) {
  __builtin_amdgcn_global_load_lds(
      (const __attribute__((address_space(1))) void*)g,
      (__attribute__((address_space(3))) void*)l, 16, 0, 0);
}

// ---------------- init: zero accumulators + score diagonal ----------------
__global__ void k_prep(float* acc, int nacc, float* out) {
  int id = blockIdx.x * 256 + threadIdx.x;
  if (id < nacc) acc[id] = 0.f;
  if (id < 1024) {
    int b = id >> 6, i = id & 63;
    out[((size_t)b * 64 + i) * 64 + i] = 0.f;
  }
}

// ---------------- GIN aggregation ----------------
__global__ void k_agg(const float* __restrict__ x, const float* __restrict__ adjs,
                      const float* __restrict__ flags,
                      float* __restrict__ h0, float* __restrict__ concat) {
  const int bi = blockIdx.x;           // 0..1023  (b*64+i)
  const int b = bi >> 6, i = bi & 63;
  const int f = threadIdx.x;           // 0..127
  __shared__ float sa[64], sm[64];
  if (f < 64) {
    float m = flags[b * 64 + i] * flags[b * 64 + f];
    float a = adjs[(size_t)(b * 64 + i) * 64 + f] * m;
    sa[f] = a; sm[f] = m;
  }
  __syncthreads();
  float s0 = 0.f, s1 = 0.f;
  const float* xb = x + (size_t)b * 64 * 128;
  for (int j = 0; j < 64; ++j) {
    float xv = xb[j * 128 + f];
    s0 = fmaf(sa[j], xv, s0);
    s1 = fmaf(sm[j] - sa[j], xv, s1);
  }
  h0[(size_t)bi * 256 + f]       = s0;
  h0[(size_t)bi * 256 + 128 + f] = s1;
  concat[(size_t)bi * 384 + f]   = xb[i * 128 + f];
}

// ---------------- small fp32 GEMM ----------------
__global__ __launch_bounds__(256) void k_sgemm(
    const float* __restrict__ A, const float* __restrict__ Bm,
    float* __restrict__ Cf, ushort_t* __restrict__ Cb,
    const float* __restrict__ bias, const float* __restrict__ rowscale,
    int K, int lda, int ldb, int ldc, int act) {
  __shared__ float As[64 * 17];
  __shared__ float Bs[16 * 64];
  const int tid = threadIdx.x;
  const int tx = tid & 15, ty = tid >> 4;
  const int m0 = blockIdx.y * 64, n0 = blockIdx.x * 64;
  float acc[4][4] = {};
  for (int k0 = 0; k0 < K; k0 += 16) {
#pragma unroll
    for (int i = 0; i < 4; i++) {
      int e = tid + i * 256;
      int r = e >> 4, c = e & 15;
      As[r * 17 + c] = A[(size_t)(m0 + r) * lda + k0 + c];
      int rb = e >> 6, cb = e & 63;
      Bs[e] = Bm[(size_t)(k0 + rb) * ldb + n0 + cb];
    }
    __syncthreads();
#pragma unroll
    for (int kk = 0; kk < 16; kk++) {
      float av[4], bv[4];
#pragma unroll
      for (int i = 0; i < 4; i++) av[i] = As[(ty * 4 + i) * 17 + kk];
#pragma unroll
      for (int j = 0; j < 4; j++) bv[j] = Bs[kk * 64 + tx * 4 + j];
#pragma unroll
      for (int i = 0; i < 4; i++)
#pragma unroll
        for (int j = 0; j < 4; j++) acc[i][j] = fmaf(av[i], bv[j], acc[i][j]);
    }
    __syncthreads();
  }
#pragma unroll
  for (int i = 0; i < 4; i++) {
    const int mm = m0 + ty * 4 + i;
    const float rs = rowscale ? rowscale[mm] : 1.f;
#pragma unroll
    for (int j = 0; j < 4; j++) {
      const int nn = n0 + tx * 4 + j;
      float v = acc[i][j] + (bias ? bias[nn] : 0.f);
      if (act == 1) v = elu_f(v);
      else if (act == 2) v = tanhf(v);
      v *= rs;
      if (Cf) Cf[(size_t)mm * ldc + nn] = v;
      if (Cb) Cb[(size_t)mm * ldc + nn] = f2bf(v);
    }
  }
}

// ---------------- merged weight prep: 3 transposes + 1 cast (grid.z switch) ----------------
__device__ __forceinline__ void castT_body(const float* in, ushort_t* out,
                                           int R, int C, int Cpad, int r0, int ld,
                                           int bx, int by) {
  __shared__ float t[32][33];
  const int rb = by * 32, cb = bx * 32;
  const int tx = threadIdx.x, ty = threadIdx.y;
#pragma unroll
  for (int dy = 0; dy < 32; dy += 8) {
    int r = rb + ty + dy, c = cb + tx;
    t[ty + dy][tx] = (r < R && c < C) ? in[(size_t)(r0 + r) * ld + c] : 0.f;
  }
  __syncthreads();
#pragma unroll
  for (int dy = 0; dy < 32; dy += 8) {
    int c = cb + ty + dy, r = rb + tx;
    if (c < Cpad && r < R) out[(size_t)c * R + r] = f2bf(t[tx][ty + dy]);
  }
}

__global__ void k_wprep(const float* __restrict__ W1t, const float* __restrict__ W1r,
                        const float* __restrict__ W2t,
                        ushort_t* __restrict__ W1tT, ushort_t* __restrict__ WrxT,
                        ushort_t* __restrict__ W2t_bf) {
  const int z = blockIdx.z;
  if (z == 0) {
    if (blockIdx.x < 48) castT_body(W1t, W1tT, 768, 1536, 1536, 2, 1536, blockIdx.x, blockIdx.y);
  } else if (z == 1) {
    if (blockIdx.x < 48) castT_body(W1t, W1tT + (size_t)1536 * 768, 768, 1536, 1536, 770, 1536, blockIdx.x, blockIdx.y);
  } else if (z == 2) {
    castT_body(W1r, WrxT, 768, 1540, NQPAD, 2, 1540, blockIdx.x, blockIdx.y);
  } else {
    int id = (blockIdx.y * 52 + blockIdx.x) * 256 + threadIdx.y * 32 + threadIdx.x;
    for (int e = id; e < 1536 * 768; e += 52 * 24 * 256)
      W2t_bf[e] = f2bf(W2t[e]);
  }
}

// ---------------- bf16 MFMA GEMM, row-major inputs (small GEMMs only) ----------------
__global__ __launch_bounds__(256) void k_gemm(
    const ushort_t* __restrict__ A, const ushort_t* __restrict__ BT,
    float* __restrict__ outF, ushort_t* __restrict__ outB,
    int K, int lda, int ldb, int ldc, int ncap, int tiledB) {
  __shared__ __align__(16) ushort_t As[128 * 32];   // 8 pages x 512 elems
  __shared__ __align__(16) ushort_t Bs[128 * 32];
  const int tid = threadIdx.x;
  const int lane = tid & 63;
  const int wv = tid >> 6;
  const int m0 = blockIdx.y * 128;
  const int n0 = blockIdx.x * 128;
  const int wm = wv >> 1, wn = wv & 1;

  f32x4 z4 = {0.f, 0.f, 0.f, 0.f};
  f32x4 acc[4][4];
#pragma unroll
  for (int i = 0; i < 4; i++)
#pragma unroll
    for (int j = 0; j < 4; j++) acc[i][j] = z4;

  const int srow = lane & 15;
  const int schunk = lane >> 4;
  const ushort_t* gA0 = A + (size_t)(m0 + 2 * wv * 16 + srow) * lda + schunk * 8;
  const ushort_t* gA1 = gA0 + (size_t)16 * lda;
  const ushort_t* gB0 = BT + (size_t)(n0 + 2 * wv * 16 + srow) * ldb + schunk * 8;
  const ushort_t* gB1 = gB0 + (size_t)16 * ldb;
  ushort_t* lA0 = &As[(2 * wv) * 512];
  ushort_t* lA1 = &As[(2 * wv + 1) * 512];
  ushort_t* lB0 = &Bs[(2 * wv) * 512];
  ushort_t* lB1 = &Bs[(2 * wv + 1) * 512];

  for (int k0 = 0; k0 < K; k0 += 32) {
    cp16_lds(gA0 + k0, lA0);
    cp16_lds(gA1 + k0, lA1);
    cp16_lds(gB0 + k0, lB0);
    cp16_lds(gB1 + k0, lB1);
    __syncthreads();
    bf16x8 af[4], bfv[4];
#pragma unroll
    for (int f = 0; f < 4; ++f) {
      af[f]  = *reinterpret_cast<const bf16x8*>(&As[(wm * 4 + f) * 512 + lane * 8]);
      bfv[f] = *reinterpret_cast<const bf16x8*>(&Bs[(wn * 4 + f) * 512 + lane * 8]);
    }
#pragma unroll
    for (int fm = 0; fm < 4; ++fm)
#pragma unroll
      for (int fn = 0; fn < 4; ++fn)
        acc[fm][fn] = __builtin_amdgcn_mfma_f32_16x16x32_bf16(af[fm], bfv[fn], acc[fm][fn], 0, 0, 0);
    __syncthreads();
  }

  const int er = (lane >> 4) * 4;
  const int ec = lane & 15;
#pragma unroll
  for (int fm = 0; fm < 4; ++fm) {
#pragma unroll
    for (int fn = 0; fn < 4; ++fn) {
      const int nn = n0 + wn * 64 + fn * 16 + ec;
      if (nn >= ncap) continue;
#pragma unroll
      for (int r = 0; r < 4; ++r) {
        const int mm = m0 + wm * 64 + fm * 16 + er + r;
        float v = acc[fm][fn][r];
        if (outF) outF[(size_t)mm * ldc + nn] = v;
        if (outB) {
          if (tiledB)
            outB[((size_t)(mm >> 4) * KC + (nn >> 3)) * 128 + (mm & 15) * 8 + (nn & 7)] = f2bf(v);
          else
            outB[(size_t)mm * ldc + nn] = f2bf(v);
        }
      }
    }
  }
}

// ---------------- bf16 MFMA GEMM, BOTH inputs fragment-tiled, bf16 row-major out ----------------
__global__ __launch_bounds__(256) void k_gemm_t(
    const ushort_t* __restrict__ At, const ushort_t* __restrict__ Bt,
    ushort_t* __restrict__ outB, int ldc, int ncap, int swz) {
  __shared__ __align__(16) ushort_t As[128 * 32];
  __shared__ __align__(16) ushort_t Bs[128 * 32];
  const int tid = threadIdx.x;
  const int lane = tid & 63;
  const int wv = tid >> 6;

  int bx = blockIdx.x, by = blockIdx.y;
  if (swz && (gridDim.y & 7) == 0) {
    int nb = gridDim.x;
    int linear = bx + nb * by;
    int xcd = linear & 7;
    int slot = linear >> 3;
    int mper = gridDim.y >> 3;
    int mp = slot / nb;
    int n  = slot - mp * nb;
    bx = n; by = xcd * mper + mp;
  }
  const int m0 = by * 128;
  const int n0 = bx * 128;
  const int wm = wv >> 1, wn = wv & 1;

  f32x4 z4 = {0.f, 0.f, 0.f, 0.f};
  f32x4 acc[4][4];
#pragma unroll
  for (int i = 0; i < 4; i++)
#pragma unroll
    for (int j = 0; j < 4; j++) acc[i][j] = z4;

  const ushort_t* gA0 = At + ((size_t)(by * 8 + 2 * wv) * KC) * 128 + lane * 8;
  const ushort_t* gA1 = gA0 + (size_t)KC * 128;
  const ushort_t* gB0 = Bt + ((size_t)(bx * 8 + 2 * wv) * KC) * 128 + lane * 8;
  const ushort_t* gB1 = gB0 + (size_t)KC * 128;
  ushort_t* lA0 = &As[(2 * wv) * 512];
  ushort_t* lA1 = &As[(2 * wv + 1) * 512];
  ushort_t* lB0 = &Bs[(2 * wv) * 512];
  ushort_t* lB1 = &Bs[(2 * wv + 1) * 512];

  for (int c0 = 0; c0 < KC; c0 += 4) {    // 4 chunks = 32 k-elems per step
    const size_t go = (size_t)c0 * 128;
    cp16_lds(gA0 + go, lA0);
    cp16_lds(gA1 + go, lA1);
    cp16_lds(gB0 + go, lB0);
    cp16_lds(gB1 + go, lB1);
    __syncthreads();
    bf16x8 af[4], bfv[4];
#pragma unroll
    for (int f = 0; f < 4; ++f) {
      af[f]  = *reinterpret_cast<const bf16x8*>(&As[(wm * 4 + f) * 512 + lane * 8]);
      bfv[f] = *reinterpret_cast<const bf16x8*>(&Bs[(wn * 4 + f) * 512 + lane * 8]);
    }
#pragma unroll
    for (int fm = 0; fm < 4; ++fm)
#pragma unroll
      for (int fn = 0; fn < 4; ++fn)
        acc[fm][fn] = __builtin_amdgcn_mfma_f32_16x16x32_bf16(af[fm], bfv[fn], acc[fm][fn], 0, 0, 0);
    __syncthreads();
  }

  // C/D layout: col = lane&15, row = (lane>>4)*4 + reg  [m89-verified]
  const int er = (lane >> 4) * 4;
  const int ec = lane & 15;
#pragma unroll
  for (int fm = 0; fm < 4; ++fm) {
#pragma unroll
    for (int fn = 0; fn < 4; ++fn) {
      const int nn = n0 + wn * 64 + fn * 16 + ec;
      if (nn >= ncap) continue;
#pragma unroll
      for (int r = 0; r < 4; ++r) {
        const int mm = m0 + wm * 64 + fm * 16 + er + r;
        outB[(size_t)mm * ldc + nn] = f2bf(acc[fm][fn][r]);
      }
    }
  }
}

// ---------------- pair data: a0_ij, a0_ji, m, packed(i*64+j) per (batch, pair-row) ----------------
__global__ void k_pdat(const float* __restrict__ adjs, const float* __restrict__ flags,
                       float4* __restrict__ pdat) {
  const int b = blockIdx.x;
  const int p = blockIdx.y * 256 + threadIdx.x;   // 0..2047
  float4 v;
  if (p < NPAIR) {
    int i = (int)((127.f - sqrtf(16129.f - 8.f * (float)p)) * 0.5f);
    if (i < 0) i = 0;
    while (63 * (i + 1) - (((i + 1) * i) >> 1) <= p) ++i;
    while (63 * i - ((i * (i - 1)) >> 1) > p) --i;
    int j = p - (63 * i - ((i * (i - 1)) >> 1)) + i + 1;
    float m = flags[b * 64 + i] * flags[b * 64 + j];
    float a0ij = adjs[((size_t)b * 64 + i) * 64 + j] * m;
    float a0ji = adjs[((size_t)b * 64 + j) * 64 + i] * m;
    v = make_float4(a0ij, a0ji, m, __int_as_float(i * 64 + j));
  } else {
    v = make_float4(0.f, 0.f, 0.f, __int_as_float(-1));
  }
  pdat[(size_t)b * PROW + p] = v;
}

// ---------------- score from pair q rows: vectorized read + wave reduction ----------------
__global__ __launch_bounds__(256) void k_score2(
    const ushort_t* __restrict__ q, const float4* __restrict__ pdat,
    const float* __restrict__ W1r, const float* __restrict__ b1r,
    const float* __restrict__ W2r, const float* __restrict__ dvec2,
    const float* __restrict__ b2r, float* __restrict__ out, int b0) {
  const int p = blockIdx.x;          // 0..2015
  const int bl = blockIdx.y;
  const int b = b0 + bl;
  const int t = threadIdx.x;
  float4 pd = pdat[(size_t)b * PROW + p];
  const int ij = __float_as_int(pd.w);
  const int i = ij >> 6, j = ij & 63;
  const float m = pd.z;
  const float a0ij = pd.x, a1ij = m - pd.x;
  const float a0ji = pd.y, a1ji = m - pd.y;
  float s1 = 0.f, s2 = 0.f;
  const int n0 = t * 8;
  if (n0 < 1540) {
    const ushort_t* qp = q + ((size_t)bl * PROW + p) * QLD + n0;
    uint4 qv = *(const uint4*)qp;
#pragma unroll
    for (int k = 0; k < 8; ++k) {
      int n = n0 + k;
      if (n < 1540) {
        float quv = bf2f(((const ushort_t*)&qv)[k]) + dvec2[n];
        float base = fmaf(m, quv, b1r[n]);
        float w0 = W1r[n], w1 = W1r[1540 + n], w2 = W2r[n];
        float z1 = base + a0ij * w0 + a1ij * w1;
        float z2 = base + a0ji * w0 + a1ji * w1;
        s1 = fmaf(elu_f(z1), w2, s1);
        s2 = fmaf(elu_f(z2), w2, s2);
      }
    }
  }
#pragma unroll
  for (int mask = 1; mask < 64; mask <<= 1) {
    s1 += __shfl_xor(s1, mask, 64);
    s2 += __shfl_xor(s2, mask, 64);
  }
  __shared__ float r1[4], r2[4];
  if ((t & 63) == 0) { r1[t >> 6] = s1; r2[t >> 6] = s2; }
  __syncthreads();
  if (t == 0) {
    out[((size_t)b * 64 + i) * 64 + j] = r1[0] + r1[1] + r1[2] + r1[3] + b2r[0];
    out[((size_t)b * 64 + j) * 64 + i] = r2[0] + r2[1] + r2[2] + r2[3] + b2r[0];
  }
}

// ---------------- dvec2: k-split matvec, dvec2[n] += 2 * sum over 96 rows ----------------
__global__ void k_dvec(const float* __restrict__ b2t, const float* __restrict__ W1r,
                       float* __restrict__ dvec2) {
  int n = blockIdx.x * 256 + threadIdx.x;
  if (n >= 1540) return;
  int m0 = blockIdx.y * 96;
  float s = 0.f;
  for (int m2 = m0; m2 < m0 + 96; ++m2)
    s = fmaf(b2t[m2], W1r[(size_t)(2 + m2) * 1540 + n], s);
  atomicAdd(&dvec2[n], 2.f * s);
}

// ---------------- adjacency moment sums (per batch) for closed-form BN stats ----------------
__global__ __launch_bounds__(64) void k_adjsum(
    const float* __restrict__ adjs, const float* __restrict__ flags,
    float* __restrict__ r0s, float* __restrict__ r1s,
    float* __restrict__ c0s, float* __restrict__ c1s, float* __restrict__ scal) {
  const int b = blockIdx.x, t = threadIdx.x;
  __shared__ float f[64];
  __shared__ float red[192];
  f[t] = flags[b * 64 + t];
  __syncthreads();
  const float ft = f[t];
  float r0 = 0, r1 = 0, q0 = 0, q1 = 0, pp = 0;
  for (int j = 0; j < 64; ++j) {
    float m = ft * f[j];
    float a = adjs[((size_t)b * 64 + t) * 64 + j] * m;
    float a1 = m - a;
    r0 += a; r1 += a1;
    q0 = fmaf(a, a, q0); q1 = fmaf(a1, a1, q1); pp = fmaf(a, a1, pp);
  }
  r0s[b * 64 + t] = r0; r1s[b * 64 + t] = r1;
  float c0 = 0, c1 = 0;
  for (int i = 0; i < 64; ++i) {
    float m = f[i] * ft;
    float a = adjs[((size_t)b * 64 + i) * 64 + t] * m;
    c0 += a; c1 += m - a;
  }
  c0s[b * 64 + t] = c0; c1s[b * 64 + t] = c1;
  red[t] = r0; red[64 + t] = r1; red[128 + t] = q0;
  __syncthreads();
  for (int s = 32; s > 0; s >>= 1) {
    if (t < s) { red[t] += red[t + s]; red[64 + t] += red[64 + t + s]; red[128 + t] += red[128 + t + s]; }
    __syncthreads();
  }
  if (t == 0) { scal[b * 5 + 0] = red[0]; scal[b * 5 + 1] = red[64]; scal[b * 5 + 2] = red[128]; }
  __syncthreads();
  red[t] = q1; red[64 + t] = pp;
  __syncthreads();
  for (int s = 32; s > 0; s >>= 1) {
    if (t < s) { red[t] += red[t + s]; red[64 + t] += red[64 + t + s]; }
    __syncthreads();
  }
  if (t == 0) { scal[b * 5 + 3] = red[0]; scal[b * 5 + 4] = red[64]; }
}

// ---------------- closed-form BN stats: ONE pass over UV ----------------
__global__ __launch_bounds__(256) void k_stats2(
    const float* __restrict__ UV, const float* __restrict__ W1t,
    const float* __restrict__ b1t,
    const float* __restrict__ r0s, const float* __restrict__ r1s,
    const float* __restrict__ c0s, const float* __restrict__ c1s,
    const float* __restrict__ scal,
    float* __restrict__ colsum, float* __restrict__ colss) {
  const int b = blockIdx.x;
  const int n = blockIdx.y * 256 + threadIdx.x;
  const int t = threadIdx.x;
  __shared__ float sr0[64], sr1[64], sc0[64], sc1[64];
  if (t < 64) {
    sr0[t] = r0s[b * 64 + t]; sr1[t] = r1s[b * 64 + t];
    sc0[t] = c0s[b * 64 + t]; sc1[t] = c1s[b * 64 + t];
  }
  __syncthreads();
  const float S0 = scal[b * 5], S1 = scal[b * 5 + 1], Q0 = scal[b * 5 + 2],
              Q1 = scal[b * 5 + 3], P = scal[b * 5 + 4];
  const float w0 = W1t[n], w1 = W1t[1536 + n], beta = b1t[n];
  float eU = 0, eV = 0, qU = 0, qV = 0, ur0 = 0, ur1 = 0, vc0 = 0, vc1 = 0;
  const float* base = UV + (size_t)b * 64 * 3072;
  for (int idx = 0; idx < 64; ++idx) {
    float U = base[(size_t)idx * 3072 + n];
    float V = base[(size_t)idx * 3072 + 1536 + n];
    eU += U; eV += V;
    qU = fmaf(U, U, qU); qV = fmaf(V, V, qV);
    ur0 = fmaf(U, sr0[idx], ur0); ur1 = fmaf(U, sr1[idx], ur1);
    vc0 = fmaf(V, sc0[idx], vc0); vc1 = fmaf(V, sc1[idx], vc1);
  }
  float hsum = 64.f * (eU + eV) + S0 * w0 + S1 * w1 + 4096.f * beta;
  float hss = 64.f * (qU + qV) + Q0 * w0 * w0 + Q1 * w1 * w1 + 4096.f * beta * beta
    + 2.f * (eU * eV + w0 * ur0 + w1 * ur1 + w0 * vc0 + w1 * vc1
             + 64.f * beta * (eU + eV) + w0 * w1 * P + beta * (w0 * S0 + w1 * S1));
  atomicAdd(&colsum[n], hsum);
  atomicAdd(&colss[n], hss);
}

// ---------------- finalize BN scale/shift ----------------
__global__ void k_bnfin(const float* __restrict__ colsum, const float* __restrict__ colss,
                        const float* __restrict__ gamma, const float* __restrict__ beta,
                        float* __restrict__ bns, float* __restrict__ bnt) {
  int n = blockIdx.x * 256 + threadIdx.x;
  if (n >= 1536) return;
  float mu = colsum[n] * (1.f / 65536.f);
  float var = colss[n] * (1.f / 65536.f) - mu * mu;
  float s = gamma[n] * rsqrtf(var + 1e-5f);
  bns[n] = s;
  bnt[n] = beta[n] - mu * s;
}

// ---------------- pair-summed hmid (fragment-tiled), i-row register caching ----------------
__global__ __launch_bounds__(256) void k_act4(
    const float* __restrict__ UV, const float4* __restrict__ pdat,
    const float* __restrict__ W1t, const float* __restrict__ b1t,
    const float* __restrict__ bns, const float* __restrict__ bnt,
    ushort_t* __restrict__ hmid_s, int b0) {
  const int g = blockIdx.x;            // chunk-local group
  const int b = b0 + (g >> 7);         // 128 groups per batch
  const int p0 = (g & 127) * 16;
  const int t = threadIdx.x;
  __shared__ __align__(16) ushort_t tile[KC * 128];   // 48 KB
  __shared__ float4 spd[16];
  if (t < 16) spd[t] = pdat[(size_t)b * PROW + p0 + t];
  __syncthreads();
  const float* base = UV + (size_t)b * 64 * 3072;
  // c-outer: per-column constants + Ui/Vi cached across pairs sharing row i
  for (int c = 0; c < 6; ++c) {
    const int n = t + 256 * c;
    const float w0 = W1t[n], w1 = W1t[1536 + n];
    const float ss = bns[n], tt = bnt[n];
    const float bb = b1t[n];
    const int cc = n >> 3;
    const int lo = n & 7;
    int ilast = -1;
    float ui = 0.f, vi = 0.f;
    for (int ei = 0; ei < 16; ++ei) {
      float4 pd = spd[ei];
      int ij = __float_as_int(pd.w);
      int s = (ei + cc) & 15;
      if (ij >= 0) {
        int i = ij >> 6, j = ij & 63;
        if (i != ilast) {
          ui = base[(size_t)i * 3072 + n];
          vi = base[(size_t)i * 3072 + 1536 + n];
          ilast = i;
        }
        float uj = base[(size_t)j * 3072 + n];
        float vj = base[(size_t)j * 3072 + 1536 + n];
        float m = pd.z;
        float h1 = ui + vj + pd.x * w0 + (m - pd.x) * w1 + bb;
        float h2 = uj + vi + pd.y * w0 + (m - pd.y) * w1 + bb;
        float v = elu_f(fmaf(h1, ss, tt)) + elu_f(fmaf(h2, ss, tt));
        tile[cc * 128 + s * 8 + lo] = f2bf(v);
      } else {
        tile[cc * 128 + s * 8 + lo] = 0;
      }
    }
  }
  __syncthreads();
  uint4* gout = (uint4*)(hmid_s + (size_t)g * (KC * 128));
  const uint4* lt = (const uint4*)tile;
#pragma unroll
  for (int it = 0; it < 12; ++it) {          // 3072 16B units
    int u = t + 256 * it;
    int cc = u >> 4, r = u & 15;
    gout[u] = lt[cc * 16 + ((r + cc) & 15)];
  }
}

extern "C" void kernel_launch(void* const* d_in, const int* in_sizes, int n_in,
                              void* d_out, int out_size, void* d_ws, size_t ws_size,
                              hipStream_t stream) {
  const float* x     = (const float*)d_in[0];
  const float* adjs  = (const float*)d_in[1];
  const float* flags = (const float*)d_in[2];
  const float* Wg    = (const float*)d_in[3];
  const float* bg    = (const float*)d_in[4];
  const float* Wout  = (const float*)d_in[5];
  const float* bout  = (const float*)d_in[6];
  const float* W1t   = (const float*)d_in[7];
  const float* b1t   = (const float*)d_in[8];
  const float* gamma = (const float*)d_in[9];
  const float* beta  = (const float*)d_in[10];
  const float* W2t   = (const float*)d_in[11];
  const float* b2t   = (const float*)d_in[12];
  const float* W1r   = (const float*)d_in[13];
  const float* b1r   = (const float*)d_in[14];
  const float* W2r   = (const float*)d_in[15];
  const float* b2r   = (const float*)d_in[16];
  float* out_score = (float*)d_out;
  float* out_xo    = (float*)d_out + 65536;

  uint8_t* ws = (uint8_t*)d_ws;
  size_t off = 0;
  auto alloc = [&](size_t bytes) -> void* {
    void* p = ws + off;
    off += (bytes + 255) & ~(size_t)255;
    return p;
  };
  float*    h0      = (float*)   alloc((size_t)1024 * 256 * 4);
  float*    concat  = (float*)   alloc((size_t)1024 * 384 * 4);
  ushort_t* xo_bf   = (ushort_t*)alloc((size_t)1024 * 768 * 2);
  ushort_t* W1tT    = (ushort_t*)alloc((size_t)3072 * 768 * 2);
  ushort_t* W2t_bf  = (ushort_t*)alloc((size_t)1536 * 768 * 2);
  ushort_t* WrxT    = (ushort_t*)alloc((size_t)NQPAD * 768 * 2);
  ushort_t* WcT     = (ushort_t*)alloc((size_t)NQPAD * 1536 * 2);  // fragment-tiled
  float*    UV      = (float*)   alloc((size_t)1024 * 3072 * 4);
  float*    dvec2   = (float*)   alloc((size_t)1664 * 4);   // contiguous with colsum/colss
  float*    colsum  = (float*)   alloc((size_t)1536 * 4);
  float*    colss   = (float*)   alloc((size_t)1536 * 4);
  float*    bns     = (float*)   alloc((size_t)1536 * 4);
  float*    bnt     = (float*)   alloc((size_t)1536 * 4);
  float*    r0s     = (float*)   alloc((size_t)1024 * 4);
  float*    r1s     = (float*)   alloc((size_t)1024 * 4);
  float*    c0s     = (float*)   alloc((size_t)1024 * 4);
  float*    c1s     = (float*)   alloc((size_t)1024 * 4);
  float*    scal    = (float*)   alloc((size_t)80 * 4);
  float4*   pdat    = (float4*)  alloc((size_t)16 * PROW * 16);

  // Adaptive chunk size (batches per chunk): hmid_s + q buffers must fit
  int cb = 2;
  {
    const int cands[4] = {16, 8, 4, 2};
    for (int ci = 0; ci < 4; ++ci) {
      int c = cands[ci];
      size_t need = off + ((size_t)c * PROW * 1536 * 2 + 256)
                        + ((size_t)c * PROW * QLD * 2 + 256);
      if (need <= ws_size) { cb = c; break; }
    }
  }
  ushort_t* hmid_s  = (ushort_t*)alloc((size_t)cb * PROW * 1536 * 2);   // fragment-tiled
  ushort_t* q_c     = (ushort_t*)alloc((size_t)cb * PROW * QLD * 2);    // row-major
  (void)in_sizes; (void)n_in; (void)out_size;

  // init accumulators + score diagonal (ws/out re-poisoned every launch)
  k_prep<<<dim3(19), dim3(256), 0, stream>>>(dvec2, 1664 + 1536 + 1536, out_score);

  // GIN chain (fp32 — x_o is a direct output)
  k_agg<<<dim3(1024), dim3(128), 0, stream>>>(x, adjs, flags, h0, concat);
  k_sgemm<<<dim3(4, 16), dim3(256), 0, stream>>>(h0, Wg, concat + 128, (ushort_t*)nullptr,
                                                 bg, flags, 256, 256, 256, 384, 1);
  k_sgemm<<<dim3(12, 16), dim3(256), 0, stream>>>(concat, Wout, out_xo, xo_bf,
                                                  bout, flags, 384, 384, 768, 768, 2);

  // merged weight prep + adjacency moments + pair data
  k_wprep<<<dim3(52, 24, 4), dim3(32, 8), 0, stream>>>(W1t, W1r, W2t, W1tT, WrxT, W2t_bf);
  k_adjsum<<<dim3(16), dim3(64), 0, stream>>>(adjs, flags, r0s, r1s, c0s, c1s, scal);
  k_pdat<<<dim3(16, 8), dim3(256), 0, stream>>>(adjs, flags, pdat);

  // UV = x_o @ [W1t_i | W1t_j]   (fp32 out, row-major)
  k_gemm<<<dim3(24, 8), dim3(256), 0, stream>>>(xo_bf, W1tT, UV, (ushort_t*)nullptr,
                                                768, 768, 768, 3072, 3072, 0);
  // WcT = (W2t @ W1r[2:770])^T  -> fragment-tiled bf16
  k_gemm<<<dim3(12, 13), dim3(256), 0, stream>>>(WrxT, W2t_bf, (float*)nullptr, WcT,
                                                 768, 768, 768, 1536, 1536, 1);
  k_dvec<<<dim3(7, 8), dim3(256), 0, stream>>>(b2t, W1r, dvec2);

  // closed-form BN stats (single UV pass), finalize
  k_stats2<<<dim3(16, 6), dim3(256), 0, stream>>>(UV, W1t, b1t, r0s, r1s, c0s, c1s, scal,
                                                  colsum, colss);
  k_bnfin<<<dim3(6), dim3(256), 0, stream>>>(colsum, colss, gamma, beta, bns, bnt);

  // heavy pipeline: pair-summed act -> pure GEMM (q bf16) -> pair score
  for (int b0 = 0; b0 < 16; b0 += cb) {
    k_act4<<<dim3(cb * 128), dim3(256), 0, stream>>>(UV, pdat, W1t, b1t, bns, bnt,
                                                     hmid_s, b0);
    k_gemm_t<<<dim3(13, cb * 16), dim3(256), 0, stream>>>(hmid_s, WcT, q_c,
                                                          QLD, 1540, 1);
    k_score2<<<dim3(NPAIR, cb), dim3(256), 0, stream>>>(q_c, pdat, W1r, b1r, W2r,
                                                        dvec2, b2r, out_score, b0);
  }
}

// Round 14
// 523.455 us; speedup vs baseline: 1.4903x; 1.4903x over previous
//
#include <hip/hip_runtime.h>
#include <cstdint>
#include <cstddef>

// Sizes (fixed by the problem)
#define NQPAD 1664        // padded N dim for GEMM grids (13 * 128)
#define QLD 1544          // q row stride (16B-aligned, 1540 valid)
#define KC 192            // K/8 chunks for the 1536-K tiled GEMM
#define NPAIR 2016        // unordered pairs per batch (64*63/2)
#define PROW 2048         // padded pair-rows per batch

typedef __bf16 bf16x8 __attribute__((ext_vector_type(8)));
typedef float  f32x4  __attribute__((ext_vector_type(4)));
typedef unsigned short ushort_t;

__device__ __forceinline__ unsigned short f2bf(float f) {
  union { float f; unsigned u; } v; v.f = f;
  unsigned r = v.u + 0x7fffu + ((v.u >> 16) & 1u);
  return (unsigned short)(r >> 16);
}
__device__ __forceinline__ float bf2f(unsigned short h) {
  union { unsigned u; float f; } v; v.u = ((unsigned)h) << 16;
  return v.f;
}
// fast elu: v_exp_f32 path (~5 instr). rel err ~1e-7.
__device__ __forceinline__ float elu_f(float x) {
  return x > 0.f ? x : __expf(x) - 1.f;
}

// async global -> LDS, 16B per lane; lds base wave-uniform (HW: base + lane*16)
__device__ __forceinline__ void cp16_lds(const ushort_t* g, ushort_t* l) {
  __builtin_amdgcn_global_load_lds(
      (const __attribute__((address_space(1))) void*)g,
      (__attribute__((address_space(3))) void*)l, 16, 0, 0);
}

// ---------------- init: zero accumulators + score diagonal ----------------
__global__ void k_prep(float* acc, int nacc, float* out) {
  int id = blockIdx.x * 256 + threadIdx.x;
  if (id < nacc) acc[id] = 0.f;
  if (id < 1024) {
    int b = id >> 6, i = id & 63;
    out[((size_t)b * 64 + i) * 64 + i] = 0.f;
  }
}

// ---------------- GIN aggregation ----------------
__global__ void k_agg(const float* __restrict__ x, const float* __restrict__ adjs,
                      const float* __restrict__ flags,
                      float* __restrict__ h0, float* __restrict__ concat) {
  const int bi = blockIdx.x;           // 0..1023  (b*64+i)
  const int b = bi >> 6, i = bi & 63;
  const int f = threadIdx.x;           // 0..127
  __shared__ float sa[64], sm[64];
  if (f < 64) {
    float m = flags[b * 64 + i] * flags[b * 64 + f];
    float a = adjs[(size_t)(b * 64 + i) * 64 + f] * m;
    sa[f] = a; sm[f] = m;
  }
  __syncthreads();
  float s0 = 0.f, s1 = 0.f;
  const float* xb = x + (size_t)b * 64 * 128;
  for (int j = 0; j < 64; ++j) {
    float xv = xb[j * 128 + f];
    s0 = fmaf(sa[j], xv, s0);
    s1 = fmaf(sm[j] - sa[j], xv, s1);
  }
  h0[(size_t)bi * 256 + f]       = s0;
  h0[(size_t)bi * 256 + 128 + f] = s1;
  concat[(size_t)bi * 384 + f]   = xb[i * 128 + f];
}

// ---------------- small fp32 GEMM ----------------
__global__ __launch_bounds__(256) void k_sgemm(
    const float* __restrict__ A, const float* __restrict__ Bm,
    float* __restrict__ Cf, ushort_t* __restrict__ Cb,
    const float* __restrict__ bias, const float* __restrict__ rowscale,
    int K, int lda, int ldb, int ldc, int act) {
  __shared__ float As[64 * 17];
  __shared__ float Bs[16 * 64];
  const int tid = threadIdx.x;
  const int tx = tid & 15, ty = tid >> 4;
  const int m0 = blockIdx.y * 64, n0 = blockIdx.x * 64;
  float acc[4][4] = {};
  for (int k0 = 0; k0 < K; k0 += 16) {
#pragma unroll
    for (int i = 0; i < 4; i++) {
      int e = tid + i * 256;
      int r = e >> 4, c = e & 15;
      As[r * 17 + c] = A[(size_t)(m0 + r) * lda + k0 + c];
      int rb = e >> 6, cb = e & 63;
      Bs[e] = Bm[(size_t)(k0 + rb) * ldb + n0 + cb];
    }
    __syncthreads();
#pragma unroll
    for (int kk = 0; kk < 16; kk++) {
      float av[4], bv[4];
#pragma unroll
      for (int i = 0; i < 4; i++) av[i] = As[(ty * 4 + i) * 17 + kk];
#pragma unroll
      for (int j = 0; j < 4; j++) bv[j] = Bs[kk * 64 + tx * 4 + j];
#pragma unroll
      for (int i = 0; i < 4; i++)
#pragma unroll
        for (int j = 0; j < 4; j++) acc[i][j] = fmaf(av[i], bv[j], acc[i][j]);
    }
    __syncthreads();
  }
#pragma unroll
  for (int i = 0; i < 4; i++) {
    const int mm = m0 + ty * 4 + i;
    const float rs = rowscale ? rowscale[mm] : 1.f;
#pragma unroll
    for (int j = 0; j < 4; j++) {
      const int nn = n0 + tx * 4 + j;
      float v = acc[i][j] + (bias ? bias[nn] : 0.f);
      if (act == 1) v = elu_f(v);
      else if (act == 2) v = tanhf(v);
      v *= rs;
      if (Cf) Cf[(size_t)mm * ldc + nn] = v;
      if (Cb) Cb[(size_t)mm * ldc + nn] = f2bf(v);
    }
  }
}

// ---------------- merged weight prep: 3 transposes + 1 cast (grid.z switch) ----------------
__device__ __forceinline__ void castT_body(const float* in, ushort_t* out,
                                           int R, int C, int Cpad, int r0, int ld,
                                           int bx, int by) {
  __shared__ float t[32][33];
  const int rb = by * 32, cb = bx * 32;
  const int tx = threadIdx.x, ty = threadIdx.y;
#pragma unroll
  for (int dy = 0; dy < 32; dy += 8) {
    int r = rb + ty + dy, c = cb + tx;
    t[ty + dy][tx] = (r < R && c < C) ? in[(size_t)(r0 + r) * ld + c] : 0.f;
  }
  __syncthreads();
#pragma unroll
  for (int dy = 0; dy < 32; dy += 8) {
    int c = cb + ty + dy, r = rb + tx;
    if (c < Cpad && r < R) out[(size_t)c * R + r] = f2bf(t[tx][ty + dy]);
  }
}

__global__ void k_wprep(const float* __restrict__ W1t, const float* __restrict__ W1r,
                        const float* __restrict__ W2t,
                        ushort_t* __restrict__ W1tT, ushort_t* __restrict__ WrxT,
                        ushort_t* __restrict__ W2t_bf) {
  const int z = blockIdx.z;
  if (z == 0) {
    if (blockIdx.x < 48) castT_body(W1t, W1tT, 768, 1536, 1536, 2, 1536, blockIdx.x, blockIdx.y);
  } else if (z == 1) {
    if (blockIdx.x < 48) castT_body(W1t, W1tT + (size_t)1536 * 768, 768, 1536, 1536, 770, 1536, blockIdx.x, blockIdx.y);
  } else if (z == 2) {
    castT_body(W1r, WrxT, 768, 1540, NQPAD, 2, 1540, blockIdx.x, blockIdx.y);
  } else {
    int id = (blockIdx.y * 52 + blockIdx.x) * 256 + threadIdx.y * 32 + threadIdx.x;
    for (int e = id; e < 1536 * 768; e += 52 * 24 * 256)
      W2t_bf[e] = f2bf(W2t[e]);
  }
}

// ---------------- bf16 MFMA GEMM, row-major inputs (small GEMMs only) ----------------
__global__ __launch_bounds__(256) void k_gemm(
    const ushort_t* __restrict__ A, const ushort_t* __restrict__ BT,
    float* __restrict__ outF, ushort_t* __restrict__ outB,
    int K, int lda, int ldb, int ldc, int ncap, int tiledB) {
  __shared__ __align__(16) ushort_t As[128 * 32];   // 8 pages x 512 elems
  __shared__ __align__(16) ushort_t Bs[128 * 32];
  const int tid = threadIdx.x;
  const int lane = tid & 63;
  const int wv = tid >> 6;
  const int m0 = blockIdx.y * 128;
  const int n0 = blockIdx.x * 128;
  const int wm = wv >> 1, wn = wv & 1;

  f32x4 z4 = {0.f, 0.f, 0.f, 0.f};
  f32x4 acc[4][4];
#pragma unroll
  for (int i = 0; i < 4; i++)
#pragma unroll
    for (int j = 0; j < 4; j++) acc[i][j] = z4;

  const int srow = lane & 15;
  const int schunk = lane >> 4;
  const ushort_t* gA0 = A + (size_t)(m0 + 2 * wv * 16 + srow) * lda + schunk * 8;
  const ushort_t* gA1 = gA0 + (size_t)16 * lda;
  const ushort_t* gB0 = BT + (size_t)(n0 + 2 * wv * 16 + srow) * ldb + schunk * 8;
  const ushort_t* gB1 = gB0 + (size_t)16 * ldb;
  ushort_t* lA0 = &As[(2 * wv) * 512];
  ushort_t* lA1 = &As[(2 * wv + 1) * 512];
  ushort_t* lB0 = &Bs[(2 * wv) * 512];
  ushort_t* lB1 = &Bs[(2 * wv + 1) * 512];

  for (int k0 = 0; k0 < K; k0 += 32) {
    cp16_lds(gA0 + k0, lA0);
    cp16_lds(gA1 + k0, lA1);
    cp16_lds(gB0 + k0, lB0);
    cp16_lds(gB1 + k0, lB1);
    __syncthreads();
    bf16x8 af[4], bfv[4];
#pragma unroll
    for (int f = 0; f < 4; ++f) {
      af[f]  = *reinterpret_cast<const bf16x8*>(&As[(wm * 4 + f) * 512 + lane * 8]);
      bfv[f] = *reinterpret_cast<const bf16x8*>(&Bs[(wn * 4 + f) * 512 + lane * 8]);
    }
#pragma unroll
    for (int fm = 0; fm < 4; ++fm)
#pragma unroll
      for (int fn = 0; fn < 4; ++fn)
        acc[fm][fn] = __builtin_amdgcn_mfma_f32_16x16x32_bf16(af[fm], bfv[fn], acc[fm][fn], 0, 0, 0);
    __syncthreads();
  }

  const int er = (lane >> 4) * 4;
  const int ec = lane & 15;
#pragma unroll
  for (int fm = 0; fm < 4; ++fm) {
#pragma unroll
    for (int fn = 0; fn < 4; ++fn) {
      const int nn = n0 + wn * 64 + fn * 16 + ec;
      if (nn >= ncap) continue;
#pragma unroll
      for (int r = 0; r < 4; ++r) {
        const int mm = m0 + wm * 64 + fm * 16 + er + r;
        float v = acc[fm][fn][r];
        if (outF) outF[(size_t)mm * ldc + nn] = v;
        if (outB) {
          if (tiledB)
            outB[((size_t)(mm >> 4) * KC + (nn >> 3)) * 128 + (mm & 15) * 8 + (nn & 7)] = f2bf(v);
          else
            outB[(size_t)mm * ldc + nn] = f2bf(v);
        }
      }
    }
  }
}

// ---------------- bf16 MFMA GEMM, BOTH inputs fragment-tiled, bf16 row-major out ----------------
__global__ __launch_bounds__(256) void k_gemm_t(
    const ushort_t* __restrict__ At, const ushort_t* __restrict__ Bt,
    ushort_t* __restrict__ outB, int ldc, int ncap, int swz) {
  __shared__ __align__(16) ushort_t As[128 * 32];
  __shared__ __align__(16) ushort_t Bs[128 * 32];
  const int tid = threadIdx.x;
  const int lane = tid & 63;
  const int wv = tid >> 6;

  int bx = blockIdx.x, by = blockIdx.y;
  if (swz && (gridDim.y & 7) == 0) {
    int nb = gridDim.x;
    int linear = bx + nb * by;
    int xcd = linear & 7;
    int slot = linear >> 3;
    int mper = gridDim.y >> 3;
    int mp = slot / nb;
    int n  = slot - mp * nb;
    bx = n; by = xcd * mper + mp;
  }
  const int m0 = by * 128;
  const int n0 = bx * 128;
  const int wm = wv >> 1, wn = wv & 1;

  f32x4 z4 = {0.f, 0.f, 0.f, 0.f};
  f32x4 acc[4][4];
#pragma unroll
  for (int i = 0; i < 4; i++)
#pragma unroll
    for (int j = 0; j < 4; j++) acc[i][j] = z4;

  const ushort_t* gA0 = At + ((size_t)(by * 8 + 2 * wv) * KC) * 128 + lane * 8;
  const ushort_t* gA1 = gA0 + (size_t)KC * 128;
  const ushort_t* gB0 = Bt + ((size_t)(bx * 8 + 2 * wv) * KC) * 128 + lane * 8;
  const ushort_t* gB1 = gB0 + (size_t)KC * 128;
  ushort_t* lA0 = &As[(2 * wv) * 512];
  ushort_t* lA1 = &As[(2 * wv + 1) * 512];
  ushort_t* lB0 = &Bs[(2 * wv) * 512];
  ushort_t* lB1 = &Bs[(2 * wv + 1) * 512];

  for (int c0 = 0; c0 < KC; c0 += 4) {    // 4 chunks = 32 k-elems per step
    const size_t go = (size_t)c0 * 128;
    cp16_lds(gA0 + go, lA0);
    cp16_lds(gA1 + go, lA1);
    cp16_lds(gB0 + go, lB0);
    cp16_lds(gB1 + go, lB1);
    __syncthreads();
    bf16x8 af[4], bfv[4];
#pragma unroll
    for (int f = 0; f < 4; ++f) {
      af[f]  = *reinterpret_cast<const bf16x8*>(&As[(wm * 4 + f) * 512 + lane * 8]);
      bfv[f] = *reinterpret_cast<const bf16x8*>(&Bs[(wn * 4 + f) * 512 + lane * 8]);
    }
#pragma unroll
    for (int fm = 0; fm < 4; ++fm)
#pragma unroll
      for (int fn = 0; fn < 4; ++fn)
        acc[fm][fn] = __builtin_amdgcn_mfma_f32_16x16x32_bf16(af[fm], bfv[fn], acc[fm][fn], 0, 0, 0);
    __syncthreads();
  }

  // C/D layout: col = lane&15, row = (lane>>4)*4 + reg  [m89-verified]
  const int er = (lane >> 4) * 4;
  const int ec = lane & 15;
#pragma unroll
  for (int fm = 0; fm < 4; ++fm) {
#pragma unroll
    for (int fn = 0; fn < 4; ++fn) {
      const int nn = n0 + wn * 64 + fn * 16 + ec;
      if (nn >= ncap) continue;
#pragma unroll
      for (int r = 0; r < 4; ++r) {
        const int mm = m0 + wm * 64 + fm * 16 + er + r;
        outB[(size_t)mm * ldc + nn] = f2bf(acc[fm][fn][r]);
      }
    }
  }
}

// ---------------- pair data: a0_ij, a0_ji, m, packed(i*64+j) per (batch, pair-row) ----------------
__global__ void k_pdat(const float* __restrict__ adjs, const float* __restrict__ flags,
                       float4* __restrict__ pdat) {
  const int b = blockIdx.x;
  const int p = blockIdx.y * 256 + threadIdx.x;   // 0..2047
  float4 v;
  if (p < NPAIR) {
    int i = (int)((127.f - sqrtf(16129.f - 8.f * (float)p)) * 0.5f);
    if (i < 0) i = 0;
    while (63 * (i + 1) - (((i + 1) * i) >> 1) <= p) ++i;
    while (63 * i - ((i * (i - 1)) >> 1) > p) --i;
    int j = p - (63 * i - ((i * (i - 1)) >> 1)) + i + 1;
    float m = flags[b * 64 + i] * flags[b * 64 + j];
    float a0ij = adjs[((size_t)b * 64 + i) * 64 + j] * m;
    float a0ji = adjs[((size_t)b * 64 + j) * 64 + i] * m;
    v = make_float4(a0ij, a0ji, m, __int_as_float(i * 64 + j));
  } else {
    v = make_float4(0.f, 0.f, 0.f, __int_as_float(-1));
  }
  pdat[(size_t)b * PROW + p] = v;
}

// ---------------- score from pair q rows: strided coalesced loads + wave reduce ----------------
// [R13 post-mortem: per-thread 8-consecutive-n made weight loads stride-8
//  uncoalesced -> 256us latency-bound. Strided n=t..+=256 keeps every load
//  wave-coalesced; reduction via shfl (1 barrier) instead of 8-barrier tree.]
__global__ __launch_bounds__(256) void k_score2(
    const ushort_t* __restrict__ q, const float4* __restrict__ pdat,
    const float* __restrict__ W1r, const float* __restrict__ b1r,
    const float* __restrict__ W2r, const float* __restrict__ dvec2,
    const float* __restrict__ b2r, float* __restrict__ out, int b0) {
  const int p = blockIdx.x;          // 0..2015
  const int bl = blockIdx.y;
  const int b = b0 + bl;
  const int t = threadIdx.x;
  float4 pd = pdat[(size_t)b * PROW + p];
  const int ij = __float_as_int(pd.w);
  const int i = ij >> 6, j = ij & 63;
  const float m = pd.z;
  const float a0ij = pd.x, a1ij = m - pd.x;
  const float a0ji = pd.y, a1ji = m - pd.y;
  const ushort_t* qp = q + ((size_t)bl * PROW + p) * QLD;
  float s1 = 0.f, s2 = 0.f;
  for (int n = t; n < 1540; n += 256) {
    float quv = bf2f(qp[n]) + dvec2[n];
    float base = fmaf(m, quv, b1r[n]);
    float w0 = W1r[n], w1 = W1r[1540 + n], w2 = W2r[n];
    float z1 = base + a0ij * w0 + a1ij * w1;
    float z2 = base + a0ji * w0 + a1ji * w1;
    s1 = fmaf(elu_f(z1), w2, s1);
    s2 = fmaf(elu_f(z2), w2, s2);
  }
#pragma unroll
  for (int mask = 1; mask < 64; mask <<= 1) {
    s1 += __shfl_xor(s1, mask, 64);
    s2 += __shfl_xor(s2, mask, 64);
  }
  __shared__ float r1[4], r2[4];
  if ((t & 63) == 0) { r1[t >> 6] = s1; r2[t >> 6] = s2; }
  __syncthreads();
  if (t == 0) {
    out[((size_t)b * 64 + i) * 64 + j] = r1[0] + r1[1] + r1[2] + r1[3] + b2r[0];
    out[((size_t)b * 64 + j) * 64 + i] = r2[0] + r2[1] + r2[2] + r2[3] + b2r[0];
  }
}

// ---------------- dvec2: k-split matvec, dvec2[n] += 2 * sum over 96 rows ----------------
__global__ void k_dvec(const float* __restrict__ b2t, const float* __restrict__ W1r,
                       float* __restrict__ dvec2) {
  int n = blockIdx.x * 256 + threadIdx.x;
  if (n >= 1540) return;
  int m0 = blockIdx.y * 96;
  float s = 0.f;
  for (int m2 = m0; m2 < m0 + 96; ++m2)
    s = fmaf(b2t[m2], W1r[(size_t)(2 + m2) * 1540 + n], s);
  atomicAdd(&dvec2[n], 2.f * s);
}

// ---------------- adjacency moment sums (per batch) for closed-form BN stats ----------------
__global__ __launch_bounds__(64) void k_adjsum(
    const float* __restrict__ adjs, const float* __restrict__ flags,
    float* __restrict__ r0s, float* __restrict__ r1s,
    float* __restrict__ c0s, float* __restrict__ c1s, float* __restrict__ scal) {
  const int b = blockIdx.x, t = threadIdx.x;
  __shared__ float f[64];
  __shared__ float red[192];
  f[t] = flags[b * 64 + t];
  __syncthreads();
  const float ft = f[t];
  float r0 = 0, r1 = 0, q0 = 0, q1 = 0, pp = 0;
  for (int j = 0; j < 64; ++j) {
    float m = ft * f[j];
    float a = adjs[((size_t)b * 64 + t) * 64 + j] * m;
    float a1 = m - a;
    r0 += a; r1 += a1;
    q0 = fmaf(a, a, q0); q1 = fmaf(a1, a1, q1); pp = fmaf(a, a1, pp);
  }
  r0s[b * 64 + t] = r0; r1s[b * 64 + t] = r1;
  float c0 = 0, c1 = 0;
  for (int i = 0; i < 64; ++i) {
    float m = f[i] * ft;
    float a = adjs[((size_t)b * 64 + i) * 64 + t] * m;
    c0 += a; c1 += m - a;
  }
  c0s[b * 64 + t] = c0; c1s[b * 64 + t] = c1;
  red[t] = r0; red[64 + t] = r1; red[128 + t] = q0;
  __syncthreads();
  for (int s = 32; s > 0; s >>= 1) {
    if (t < s) { red[t] += red[t + s]; red[64 + t] += red[64 + t + s]; red[128 + t] += red[128 + t + s]; }
    __syncthreads();
  }
  if (t == 0) { scal[b * 5 + 0] = red[0]; scal[b * 5 + 1] = red[64]; scal[b * 5 + 2] = red[128]; }
  __syncthreads();
  red[t] = q1; red[64 + t] = pp;
  __syncthreads();
  for (int s = 32; s > 0; s >>= 1) {
    if (t < s) { red[t] += red[t + s]; red[64 + t] += red[64 + t + s]; }
    __syncthreads();
  }
  if (t == 0) { scal[b * 5 + 3] = red[0]; scal[b * 5 + 4] = red[64]; }
}

// ---------------- closed-form BN stats: ONE pass over UV ----------------
__global__ __launch_bounds__(256) void k_stats2(
    const float* __restrict__ UV, const float* __restrict__ W1t,
    const float* __restrict__ b1t,
    const float* __restrict__ r0s, const float* __restrict__ r1s,
    const float* __restrict__ c0s, const float* __restrict__ c1s,
    const float* __restrict__ scal,
    float* __restrict__ colsum, float* __restrict__ colss) {
  const int b = blockIdx.x;
  const int n = blockIdx.y * 256 + threadIdx.x;
  const int t = threadIdx.x;
  __shared__ float sr0[64], sr1[64], sc0[64], sc1[64];
  if (t < 64) {
    sr0[t] = r0s[b * 64 + t]; sr1[t] = r1s[b * 64 + t];
    sc0[t] = c0s[b * 64 + t]; sc1[t] = c1s[b * 64 + t];
  }
  __syncthreads();
  const float S0 = scal[b * 5], S1 = scal[b * 5 + 1], Q0 = scal[b * 5 + 2],
              Q1 = scal[b * 5 + 3], P = scal[b * 5 + 4];
  const float w0 = W1t[n], w1 = W1t[1536 + n], beta = b1t[n];
  float eU = 0, eV = 0, qU = 0, qV = 0, ur0 = 0, ur1 = 0, vc0 = 0, vc1 = 0;
  const float* base = UV + (size_t)b * 64 * 3072;
  for (int idx = 0; idx < 64; ++idx) {
    float U = base[(size_t)idx * 3072 + n];
    float V = base[(size_t)idx * 3072 + 1536 + n];
    eU += U; eV += V;
    qU = fmaf(U, U, qU); qV = fmaf(V, V, qV);
    ur0 = fmaf(U, sr0[idx], ur0); ur1 = fmaf(U, sr1[idx], ur1);
    vc0 = fmaf(V, sc0[idx], vc0); vc1 = fmaf(V, sc1[idx], vc1);
  }
  float hsum = 64.f * (eU + eV) + S0 * w0 + S1 * w1 + 4096.f * beta;
  float hss = 64.f * (qU + qV) + Q0 * w0 * w0 + Q1 * w1 * w1 + 4096.f * beta * beta
    + 2.f * (eU * eV + w0 * ur0 + w1 * ur1 + w0 * vc0 + w1 * vc1
             + 64.f * beta * (eU + eV) + w0 * w1 * P + beta * (w0 * S0 + w1 * S1));
  atomicAdd(&colsum[n], hsum);
  atomicAdd(&colss[n], hss);
}

// ---------------- finalize BN scale/shift ----------------
__global__ void k_bnfin(const float* __restrict__ colsum, const float* __restrict__ colss,
                        const float* __restrict__ gamma, const float* __restrict__ beta,
                        float* __restrict__ bns, float* __restrict__ bnt) {
  int n = blockIdx.x * 256 + threadIdx.x;
  if (n >= 1536) return;
  float mu = colsum[n] * (1.f / 65536.f);
  float var = colss[n] * (1.f / 65536.f) - mu * mu;
  float s = gamma[n] * rsqrtf(var + 1e-5f);
  bns[n] = s;
  bnt[n] = beta[n] - mu * s;
}

// ---------------- pair-summed hmid (fragment-tiled): one block per 16-pair group ----------------
// [539-proven ei-outer structure]
__global__ __launch_bounds__(256) void k_act4(
    const float* __restrict__ UV, const float4* __restrict__ pdat,
    const float* __restrict__ W1t, const float* __restrict__ b1t,
    const float* __restrict__ bns, const float* __restrict__ bnt,
    ushort_t* __restrict__ hmid_s, int b0) {
  const int g = blockIdx.x;            // chunk-local group
  const int b = b0 + (g >> 7);         // 128 groups per batch
  const int p0 = (g & 127) * 16;
  const int t = threadIdx.x;
  __shared__ __align__(16) ushort_t tile[KC * 128];   // 48 KB
  float w06[6], w16[6], s6[6], t6[6], bb6[6];
#pragma unroll
  for (int c = 0; c < 6; c++) {
    int n = t + 256 * c;
    w06[c] = W1t[n]; w16[c] = W1t[1536 + n];
    s6[c] = bns[n]; t6[c] = bnt[n]; bb6[c] = b1t[n];
  }
  const unsigned short zbf = 0;
  for (int ei = 0; ei < 16; ++ei) {
    const int p = p0 + ei;
    float4 pd = pdat[(size_t)b * PROW + p];
    int ij = __float_as_int(pd.w);
    if (ij >= 0) {
      int i = ij >> 6, j = ij & 63;
      const float* Ui = UV + (size_t)(b * 64 + i) * 3072;
      const float* Vi = Ui + 1536;
      const float* Uj = UV + (size_t)(b * 64 + j) * 3072;
      const float* Vj = Uj + 1536;
      float m = pd.z;
      float a0ij = pd.x, a1ij = m - pd.x;
      float a0ji = pd.y, a1ji = m - pd.y;
#pragma unroll
      for (int c = 0; c < 6; c++) {
        int n = t + 256 * c;
        float h1 = Ui[n] + Vj[n] + a0ij * w06[c] + a1ij * w16[c] + bb6[c];
        float h2 = Uj[n] + Vi[n] + a0ji * w06[c] + a1ji * w16[c] + bb6[c];
        float v = elu_f(fmaf(h1, s6[c], t6[c])) + elu_f(fmaf(h2, s6[c], t6[c]));
        int cc = n >> 3;
        int s = (ei + cc) & 15;
        tile[cc * 128 + s * 8 + (n & 7)] = f2bf(v);
      }
    } else {
#pragma unroll
      for (int c = 0; c < 6; c++) {
        int n = t + 256 * c;
        int cc = n >> 3;
        int s = (ei + cc) & 15;
        tile[cc * 128 + s * 8 + (n & 7)] = zbf;
      }
    }
  }
  __syncthreads();
  uint4* gout = (uint4*)(hmid_s + (size_t)g * (KC * 128));
  const uint4* lt = (const uint4*)tile;
#pragma unroll
  for (int it = 0; it < 12; ++it) {          // 3072 16B units
    int u = t + 256 * it;
    int cc = u >> 4, r = u & 15;
    gout[u] = lt[cc * 16 + ((r + cc) & 15)];
  }
}

extern "C" void kernel_launch(void* const* d_in, const int* in_sizes, int n_in,
                              void* d_out, int out_size, void* d_ws, size_t ws_size,
                              hipStream_t stream) {
  const float* x     = (const float*)d_in[0];
  const float* adjs  = (const float*)d_in[1];
  const float* flags = (const float*)d_in[2];
  const float* Wg    = (const float*)d_in[3];
  const float* bg    = (const float*)d_in[4];
  const float* Wout  = (const float*)d_in[5];
  const float* bout  = (const float*)d_in[6];
  const float* W1t   = (const float*)d_in[7];
  const float* b1t   = (const float*)d_in[8];
  const float* gamma = (const float*)d_in[9];
  const float* beta  = (const float*)d_in[10];
  const float* W2t   = (const float*)d_in[11];
  const float* b2t   = (const float*)d_in[12];
  const float* W1r   = (const float*)d_in[13];
  const float* b1r   = (const float*)d_in[14];
  const float* W2r   = (const float*)d_in[15];
  const float* b2r   = (const float*)d_in[16];
  float* out_score = (float*)d_out;
  float* out_xo    = (float*)d_out + 65536;

  uint8_t* ws = (uint8_t*)d_ws;
  size_t off = 0;
  auto alloc = [&](size_t bytes) -> void* {
    void* p = ws + off;
    off += (bytes + 255) & ~(size_t)255;
    return p;
  };
  float*    h0      = (float*)   alloc((size_t)1024 * 256 * 4);
  float*    concat  = (float*)   alloc((size_t)1024 * 384 * 4);
  ushort_t* xo_bf   = (ushort_t*)alloc((size_t)1024 * 768 * 2);
  ushort_t* W1tT    = (ushort_t*)alloc((size_t)3072 * 768 * 2);
  ushort_t* W2t_bf  = (ushort_t*)alloc((size_t)1536 * 768 * 2);
  ushort_t* WrxT    = (ushort_t*)alloc((size_t)NQPAD * 768 * 2);
  ushort_t* WcT     = (ushort_t*)alloc((size_t)NQPAD * 1536 * 2);  // fragment-tiled
  float*    UV      = (float*)   alloc((size_t)1024 * 3072 * 4);
  float*    dvec2   = (float*)   alloc((size_t)1664 * 4);   // contiguous with colsum/colss
  float*    colsum  = (float*)   alloc((size_t)1536 * 4);
  float*    colss   = (float*)   alloc((size_t)1536 * 4);
  float*    bns     = (float*)   alloc((size_t)1536 * 4);
  float*    bnt     = (float*)   alloc((size_t)1536 * 4);
  float*    r0s     = (float*)   alloc((size_t)1024 * 4);
  float*    r1s     = (float*)   alloc((size_t)1024 * 4);
  float*    c0s     = (float*)   alloc((size_t)1024 * 4);
  float*    c1s     = (float*)   alloc((size_t)1024 * 4);
  float*    scal    = (float*)   alloc((size_t)80 * 4);
  float4*   pdat    = (float4*)  alloc((size_t)16 * PROW * 16);

  // Adaptive chunk size (batches per chunk): hmid_s + q buffers must fit
  int cb = 2;
  {
    const int cands[4] = {16, 8, 4, 2};
    for (int ci = 0; ci < 4; ++ci) {
      int c = cands[ci];
      size_t need = off + ((size_t)c * PROW * 1536 * 2 + 256)
                        + ((size_t)c * PROW * QLD * 2 + 256);
      if (need <= ws_size) { cb = c; break; }
    }
  }
  ushort_t* hmid_s  = (ushort_t*)alloc((size_t)cb * PROW * 1536 * 2);   // fragment-tiled
  ushort_t* q_c     = (ushort_t*)alloc((size_t)cb * PROW * QLD * 2);    // row-major
  (void)in_sizes; (void)n_in; (void)out_size;

  // init accumulators + score diagonal (ws/out re-poisoned every launch)
  k_prep<<<dim3(19), dim3(256), 0, stream>>>(dvec2, 1664 + 1536 + 1536, out_score);

  // GIN chain (fp32 — x_o is a direct output)
  k_agg<<<dim3(1024), dim3(128), 0, stream>>>(x, adjs, flags, h0, concat);
  k_sgemm<<<dim3(4, 16), dim3(256), 0, stream>>>(h0, Wg, concat + 128, (ushort_t*)nullptr,
                                                 bg, flags, 256, 256, 256, 384, 1);
  k_sgemm<<<dim3(12, 16), dim3(256), 0, stream>>>(concat, Wout, out_xo, xo_bf,
                                                  bout, flags, 384, 384, 768, 768, 2);

  // merged weight prep + adjacency moments + pair data
  k_wprep<<<dim3(52, 24, 4), dim3(32, 8), 0, stream>>>(W1t, W1r, W2t, W1tT, WrxT, W2t_bf);
  k_adjsum<<<dim3(16), dim3(64), 0, stream>>>(adjs, flags, r0s, r1s, c0s, c1s, scal);
  k_pdat<<<dim3(16, 8), dim3(256), 0, stream>>>(adjs, flags, pdat);

  // UV = x_o @ [W1t_i | W1t_j]   (fp32 out, row-major)
  k_gemm<<<dim3(24, 8), dim3(256), 0, stream>>>(xo_bf, W1tT, UV, (ushort_t*)nullptr,
                                                768, 768, 768, 3072, 3072, 0);
  // WcT = (W2t @ W1r[2:770])^T  -> fragment-tiled bf16
  k_gemm<<<dim3(12, 13), dim3(256), 0, stream>>>(WrxT, W2t_bf, (float*)nullptr, WcT,
                                                 768, 768, 768, 1536, 1536, 1);
  k_dvec<<<dim3(7, 8), dim3(256), 0, stream>>>(b2t, W1r, dvec2);

  // closed-form BN stats (single UV pass), finalize
  k_stats2<<<dim3(16, 6), dim3(256), 0, stream>>>(UV, W1t, b1t, r0s, r1s, c0s, c1s, scal,
                                                  colsum, colss);
  k_bnfin<<<dim3(6), dim3(256), 0, stream>>>(colsum, colss, gamma, beta, bns, bnt);

  // heavy pipeline: pair-summed act -> pure GEMM (q bf16) -> pair score
  for (int b0 = 0; b0 < 16; b0 += cb) {
    k_act4<<<dim3(cb * 128), dim3(256), 0, stream>>>(UV, pdat, W1t, b1t, bns, bnt,
                                                     hmid_s, b0);
    k_gemm_t<<<dim3(13, cb * 16), dim3(256), 0, stream>>>(hmid_s, WcT, q_c,
                                                          QLD, 1540, 1);
    k_score2<<<dim3(NPAIR, cb), dim3(256), 0, stream>>>(q_c, pdat, W1r, b1r, W2r,
                                                        dvec2, b2r, out_score, b0);
  }
}

// Round 15
// 521.146 us; speedup vs baseline: 1.4969x; 1.0044x over previous
//
#include <hip/hip_runtime.h>
#include <cstdint>
#include <cstddef>

// Sizes (fixed by the problem)
#define NQPAD 1664        // padded N dim for GEMM grids (13 * 128)
#define QLD 1544          // q row stride (16B-aligned, 1540 valid)
#define KC 192            // K/8 chunks for the 1536-K tiled GEMM
#define NPAIR 2016        // unordered pairs per batch (64*63/2)
#define PROW 2048         // padded pair-rows per batch

typedef __bf16 bf16x8 __attribute__((ext_vector_type(8)));
typedef float  f32x4  __attribute__((ext_vector_type(4)));
typedef unsigned short ushort_t;

__device__ __forceinline__ unsigned short f2bf(float f) {
  union { float f; unsigned u; } v; v.f = f;
  unsigned r = v.u + 0x7fffu + ((v.u >> 16) & 1u);
  return (unsigned short)(r >> 16);
}
__device__ __forceinline__ float bf2f(unsigned short h) {
  union { unsigned u; float f; } v; v.u = ((unsigned)h) << 16;
  return v.f;
}
// fast elu: v_exp_f32 path (~5 instr). rel err ~1e-7.
__device__ __forceinline__ float elu_f(float x) {
  return x > 0.f ? x : __expf(x) - 1.f;
}

// async global -> LDS, 16B per lane; lds base wave-uniform (HW: base + lane*16)
__device__ __forceinline__ void cp16_lds(const ushort_t* g, ushort_t* l) {
  __builtin_amdgcn_global_load_lds(
      (const __attribute__((address_space(1))) void*)g,
      (__attribute__((address_space(3))) void*)l, 16, 0, 0);
}

// ---------------- init: zero accumulators + score diagonal ----------------
__global__ void k_prep(float* acc, int nacc, float* out) {
  int id = blockIdx.x * 256 + threadIdx.x;
  if (id < nacc) acc[id] = 0.f;
  if (id < 1024) {
    int b = id >> 6, i = id & 63;
    out[((size_t)b * 64 + i) * 64 + i] = 0.f;
  }
}

// ---------------- GIN aggregation ----------------
__global__ void k_agg(const float* __restrict__ x, const float* __restrict__ adjs,
                      const float* __restrict__ flags,
                      float* __restrict__ h0, float* __restrict__ concat) {
  const int bi = blockIdx.x;           // 0..1023  (b*64+i)
  const int b = bi >> 6, i = bi & 63;
  const int f = threadIdx.x;           // 0..127
  __shared__ float sa[64], sm[64];
  if (f < 64) {
    float m = flags[b * 64 + i] * flags[b * 64 + f];
    float a = adjs[(size_t)(b * 64 + i) * 64 + f] * m;
    sa[f] = a; sm[f] = m;
  }
  __syncthreads();
  float s0 = 0.f, s1 = 0.f;
  const float* xb = x + (size_t)b * 64 * 128;
  for (int j = 0; j < 64; ++j) {
    float xv = xb[j * 128 + f];
    s0 = fmaf(sa[j], xv, s0);
    s1 = fmaf(sm[j] - sa[j], xv, s1);
  }
  h0[(size_t)bi * 256 + f]       = s0;
  h0[(size_t)bi * 256 + 128 + f] = s1;
  concat[(size_t)bi * 384 + f]   = xb[i * 128 + f];
}

// ---------------- small fp32 GEMM ----------------
__global__ __launch_bounds__(256) void k_sgemm(
    const float* __restrict__ A, const float* __restrict__ Bm,
    float* __restrict__ Cf, ushort_t* __restrict__ Cb,
    const float* __restrict__ bias, const float* __restrict__ rowscale,
    int K, int lda, int ldb, int ldc, int act) {
  __shared__ float As[64 * 17];
  __shared__ float Bs[16 * 64];
  const int tid = threadIdx.x;
  const int tx = tid & 15, ty = tid >> 4;
  const int m0 = blockIdx.y * 64, n0 = blockIdx.x * 64;
  float acc[4][4] = {};
  for (int k0 = 0; k0 < K; k0 += 16) {
#pragma unroll
    for (int i = 0; i < 4; i++) {
      int e = tid + i * 256;
      int r = e >> 4, c = e & 15;
      As[r * 17 + c] = A[(size_t)(m0 + r) * lda + k0 + c];
      int rb = e >> 6, cb = e & 63;
      Bs[e] = Bm[(size_t)(k0 + rb) * ldb + n0 + cb];
    }
    __syncthreads();
#pragma unroll
    for (int kk = 0; kk < 16; kk++) {
      float av[4], bv[4];
#pragma unroll
      for (int i = 0; i < 4; i++) av[i] = As[(ty * 4 + i) * 17 + kk];
#pragma unroll
      for (int j = 0; j < 4; j++) bv[j] = Bs[kk * 64 + tx * 4 + j];
#pragma unroll
      for (int i = 0; i < 4; i++)
#pragma unroll
        for (int j = 0; j < 4; j++) acc[i][j] = fmaf(av[i], bv[j], acc[i][j]);
    }
    __syncthreads();
  }
#pragma unroll
  for (int i = 0; i < 4; i++) {
    const int mm = m0 + ty * 4 + i;
    const float rs = rowscale ? rowscale[mm] : 1.f;
#pragma unroll
    for (int j = 0; j < 4; j++) {
      const int nn = n0 + tx * 4 + j;
      float v = acc[i][j] + (bias ? bias[nn] : 0.f);
      if (act == 1) v = elu_f(v);
      else if (act == 2) v = tanhf(v);
      v *= rs;
      if (Cf) Cf[(size_t)mm * ldc + nn] = v;
      if (Cb) Cb[(size_t)mm * ldc + nn] = f2bf(v);
    }
  }
}

// ---------------- merged weight prep: 3 transposes + cast + dvec (grid.z switch) ----------------
__device__ __forceinline__ void castT_body(const float* in, ushort_t* out,
                                           int R, int C, int Cpad, int r0, int ld,
                                           int bx, int by) {
  __shared__ float t[32][33];
  const int rb = by * 32, cb = bx * 32;
  const int tx = threadIdx.x, ty = threadIdx.y;
#pragma unroll
  for (int dy = 0; dy < 32; dy += 8) {
    int r = rb + ty + dy, c = cb + tx;
    t[ty + dy][tx] = (r < R && c < C) ? in[(size_t)(r0 + r) * ld + c] : 0.f;
  }
  __syncthreads();
#pragma unroll
  for (int dy = 0; dy < 32; dy += 8) {
    int c = cb + ty + dy, r = rb + tx;
    if (c < Cpad && r < R) out[(size_t)c * R + r] = f2bf(t[tx][ty + dy]);
  }
}

__global__ void k_wprep(const float* __restrict__ W1t, const float* __restrict__ W1r,
                        const float* __restrict__ W2t, const float* __restrict__ b2t,
                        ushort_t* __restrict__ W1tT, ushort_t* __restrict__ WrxT,
                        ushort_t* __restrict__ W2t_bf, float* __restrict__ dvec2) {
  const int z = blockIdx.z;
  if (z == 0) {
    if (blockIdx.x < 48) castT_body(W1t, W1tT, 768, 1536, 1536, 2, 1536, blockIdx.x, blockIdx.y);
  } else if (z == 1) {
    if (blockIdx.x < 48) castT_body(W1t, W1tT + (size_t)1536 * 768, 768, 1536, 1536, 770, 1536, blockIdx.x, blockIdx.y);
  } else if (z == 2) {
    castT_body(W1r, WrxT, 768, 1540, NQPAD, 2, 1540, blockIdx.x, blockIdx.y);
  } else if (z == 3) {
    int id = (blockIdx.y * 52 + blockIdx.x) * 256 + threadIdx.y * 32 + threadIdx.x;
    for (int e = id; e < 1536 * 768; e += 52 * 24 * 256)
      W2t_bf[e] = f2bf(W2t[e]);
  } else {
    // dvec2[n] += 2 * sum_{96 rows} b2t[m]*W1r[2+m, n]   (56 work blocks)
    int bid = blockIdx.y * 52 + blockIdx.x;
    if (bid >= 56) return;
    int nb = bid % 7, kb = bid / 7;
    int t = threadIdx.y * 32 + threadIdx.x;
    int n = nb * 256 + t;
    if (n >= 1540) return;
    int m0 = kb * 96;
    float s = 0.f;
    for (int m2 = m0; m2 < m0 + 96; ++m2)
      s = fmaf(b2t[m2], W1r[(size_t)(2 + m2) * 1540 + n], s);
    atomicAdd(&dvec2[n], 2.f * s);
  }
}

// ---------------- bf16 MFMA GEMM, row-major inputs (small GEMMs only) ----------------
__global__ __launch_bounds__(256) void k_gemm(
    const ushort_t* __restrict__ A, const ushort_t* __restrict__ BT,
    float* __restrict__ outF, ushort_t* __restrict__ outB,
    int K, int lda, int ldb, int ldc, int ncap, int tiledB) {
  __shared__ __align__(16) ushort_t As[128 * 32];   // 8 pages x 512 elems
  __shared__ __align__(16) ushort_t Bs[128 * 32];
  const int tid = threadIdx.x;
  const int lane = tid & 63;
  const int wv = tid >> 6;
  const int m0 = blockIdx.y * 128;
  const int n0 = blockIdx.x * 128;
  const int wm = wv >> 1, wn = wv & 1;

  f32x4 z4 = {0.f, 0.f, 0.f, 0.f};
  f32x4 acc[4][4];
#pragma unroll
  for (int i = 0; i < 4; i++)
#pragma unroll
    for (int j = 0; j < 4; j++) acc[i][j] = z4;

  const int srow = lane & 15;
  const int schunk = lane >> 4;
  const ushort_t* gA0 = A + (size_t)(m0 + 2 * wv * 16 + srow) * lda + schunk * 8;
  const ushort_t* gA1 = gA0 + (size_t)16 * lda;
  const ushort_t* gB0 = BT + (size_t)(n0 + 2 * wv * 16 + srow) * ldb + schunk * 8;
  const ushort_t* gB1 = gB0 + (size_t)16 * ldb;
  ushort_t* lA0 = &As[(2 * wv) * 512];
  ushort_t* lA1 = &As[(2 * wv + 1) * 512];
  ushort_t* lB0 = &Bs[(2 * wv) * 512];
  ushort_t* lB1 = &Bs[(2 * wv + 1) * 512];

  for (int k0 = 0; k0 < K; k0 += 32) {
    cp16_lds(gA0 + k0, lA0);
    cp16_lds(gA1 + k0, lA1);
    cp16_lds(gB0 + k0, lB0);
    cp16_lds(gB1 + k0, lB1);
    __syncthreads();
    bf16x8 af[4], bfv[4];
#pragma unroll
    for (int f = 0; f < 4; ++f) {
      af[f]  = *reinterpret_cast<const bf16x8*>(&As[(wm * 4 + f) * 512 + lane * 8]);
      bfv[f] = *reinterpret_cast<const bf16x8*>(&Bs[(wn * 4 + f) * 512 + lane * 8]);
    }
#pragma unroll
    for (int fm = 0; fm < 4; ++fm)
#pragma unroll
      for (int fn = 0; fn < 4; ++fn)
        acc[fm][fn] = __builtin_amdgcn_mfma_f32_16x16x32_bf16(af[fm], bfv[fn], acc[fm][fn], 0, 0, 0);
    __syncthreads();
  }

  const int er = (lane >> 4) * 4;
  const int ec = lane & 15;
#pragma unroll
  for (int fm = 0; fm < 4; ++fm) {
#pragma unroll
    for (int fn = 0; fn < 4; ++fn) {
      const int nn = n0 + wn * 64 + fn * 16 + ec;
      if (nn >= ncap) continue;
#pragma unroll
      for (int r = 0; r < 4; ++r) {
        const int mm = m0 + wm * 64 + fm * 16 + er + r;
        float v = acc[fm][fn][r];
        if (outF) outF[(size_t)mm * ldc + nn] = v;
        if (outB) {
          if (tiledB)
            outB[((size_t)(mm >> 4) * KC + (nn >> 3)) * 128 + (mm & 15) * 8 + (nn & 7)] = f2bf(v);
          else
            outB[(size_t)mm * ldc + nn] = f2bf(v);
        }
      }
    }
  }
}

// ---------------- bf16 MFMA GEMM, BOTH inputs fragment-tiled, bf16 row-major out ----------------
__global__ __launch_bounds__(256) void k_gemm_t(
    const ushort_t* __restrict__ At, const ushort_t* __restrict__ Bt,
    ushort_t* __restrict__ outB, int ldc, int ncap, int swz) {
  __shared__ __align__(16) ushort_t As[128 * 32];
  __shared__ __align__(16) ushort_t Bs[128 * 32];
  const int tid = threadIdx.x;
  const int lane = tid & 63;
  const int wv = tid >> 6;

  int bx = blockIdx.x, by = blockIdx.y;
  if (swz && (gridDim.y & 7) == 0) {
    int nb = gridDim.x;
    int linear = bx + nb * by;
    int xcd = linear & 7;
    int slot = linear >> 3;
    int mper = gridDim.y >> 3;
    int mp = slot / nb;
    int n  = slot - mp * nb;
    bx = n; by = xcd * mper + mp;
  }
  const int m0 = by * 128;
  const int n0 = bx * 128;
  const int wm = wv >> 1, wn = wv & 1;

  f32x4 z4 = {0.f, 0.f, 0.f, 0.f};
  f32x4 acc[4][4];
#pragma unroll
  for (int i = 0; i < 4; i++)
#pragma unroll
    for (int j = 0; j < 4; j++) acc[i][j] = z4;

  const ushort_t* gA0 = At + ((size_t)(by * 8 + 2 * wv) * KC) * 128 + lane * 8;
  const ushort_t* gA1 = gA0 + (size_t)KC * 128;
  const ushort_t* gB0 = Bt + ((size_t)(bx * 8 + 2 * wv) * KC) * 128 + lane * 8;
  const ushort_t* gB1 = gB0 + (size_t)KC * 128;
  ushort_t* lA0 = &As[(2 * wv) * 512];
  ushort_t* lA1 = &As[(2 * wv + 1) * 512];
  ushort_t* lB0 = &Bs[(2 * wv) * 512];
  ushort_t* lB1 = &Bs[(2 * wv + 1) * 512];

  for (int c0 = 0; c0 < KC; c0 += 4) {    // 4 chunks = 32 k-elems per step
    const size_t go = (size_t)c0 * 128;
    cp16_lds(gA0 + go, lA0);
    cp16_lds(gA1 + go, lA1);
    cp16_lds(gB0 + go, lB0);
    cp16_lds(gB1 + go, lB1);
    __syncthreads();
    bf16x8 af[4], bfv[4];
#pragma unroll
    for (int f = 0; f < 4; ++f) {
      af[f]  = *reinterpret_cast<const bf16x8*>(&As[(wm * 4 + f) * 512 + lane * 8]);
      bfv[f] = *reinterpret_cast<const bf16x8*>(&Bs[(wn * 4 + f) * 512 + lane * 8]);
    }
#pragma unroll
    for (int fm = 0; fm < 4; ++fm)
#pragma unroll
      for (int fn = 0; fn < 4; ++fn)
        acc[fm][fn] = __builtin_amdgcn_mfma_f32_16x16x32_bf16(af[fm], bfv[fn], acc[fm][fn], 0, 0, 0);
    __syncthreads();
  }

  // C/D layout: col = lane&15, row = (lane>>4)*4 + reg  [m89-verified]
  const int er = (lane >> 4) * 4;
  const int ec = lane & 15;
#pragma unroll
  for (int fm = 0; fm < 4; ++fm) {
#pragma unroll
    for (int fn = 0; fn < 4; ++fn) {
      const int nn = n0 + wn * 64 + fn * 16 + ec;
      if (nn >= ncap) continue;
#pragma unroll
      for (int r = 0; r < 4; ++r) {
        const int mm = m0 + wm * 64 + fm * 16 + er + r;
        outB[(size_t)mm * ldc + nn] = f2bf(acc[fm][fn][r]);
      }
    }
  }
}

// ---------------- merged: adjacency moments (y==8) + pair data (y<8) ----------------
__global__ __launch_bounds__(256) void k_adjpdat(
    const float* __restrict__ adjs, const float* __restrict__ flags,
    float* __restrict__ r0s, float* __restrict__ r1s,
    float* __restrict__ c0s, float* __restrict__ c1s, float* __restrict__ scal,
    float4* __restrict__ pdat) {
  const int b = blockIdx.x;
  const int t = threadIdx.x;
  if (blockIdx.y < 8) {
    // pair data
    const int p = blockIdx.y * 256 + t;   // 0..2047
    float4 v;
    if (p < NPAIR) {
      int i = (int)((127.f - sqrtf(16129.f - 8.f * (float)p)) * 0.5f);
      if (i < 0) i = 0;
      while (63 * (i + 1) - (((i + 1) * i) >> 1) <= p) ++i;
      while (63 * i - ((i * (i - 1)) >> 1) > p) --i;
      int j = p - (63 * i - ((i * (i - 1)) >> 1)) + i + 1;
      float m = flags[b * 64 + i] * flags[b * 64 + j];
      float a0ij = adjs[((size_t)b * 64 + i) * 64 + j] * m;
      float a0ji = adjs[((size_t)b * 64 + j) * 64 + i] * m;
      v = make_float4(a0ij, a0ji, m, __int_as_float(i * 64 + j));
    } else {
      v = make_float4(0.f, 0.f, 0.f, __int_as_float(-1));
    }
    pdat[(size_t)b * PROW + p] = v;
    return;
  }
  // adjacency moment sums (first 64 lanes active; barriers unconditional)
  __shared__ float f[64];
  __shared__ float red[192];
  const bool act = (t < 64);
  if (act) f[t] = flags[b * 64 + t];
  __syncthreads();
  float r0 = 0, r1 = 0, q0 = 0, q1 = 0, pp = 0, c0 = 0, c1 = 0;
  if (act) {
    const float ft = f[t];
    for (int j = 0; j < 64; ++j) {
      float m = ft * f[j];
      float a = adjs[((size_t)b * 64 + t) * 64 + j] * m;
      float a1 = m - a;
      r0 += a; r1 += a1;
      q0 = fmaf(a, a, q0); q1 = fmaf(a1, a1, q1); pp = fmaf(a, a1, pp);
    }
    r0s[b * 64 + t] = r0; r1s[b * 64 + t] = r1;
    for (int i = 0; i < 64; ++i) {
      float m = f[i] * ft;
      float a = adjs[((size_t)b * 64 + i) * 64 + t] * m;
      c0 += a; c1 += m - a;
    }
    c0s[b * 64 + t] = c0; c1s[b * 64 + t] = c1;
    red[t] = r0; red[64 + t] = r1; red[128 + t] = q0;
  }
  __syncthreads();
  for (int s = 32; s > 0; s >>= 1) {
    if (act && t < s) { red[t] += red[t + s]; red[64 + t] += red[64 + t + s]; red[128 + t] += red[128 + t + s]; }
    __syncthreads();
  }
  if (t == 0) { scal[b * 5 + 0] = red[0]; scal[b * 5 + 1] = red[64]; scal[b * 5 + 2] = red[128]; }
  __syncthreads();
  if (act) { red[t] = q1; red[64 + t] = pp; }
  __syncthreads();
  for (int s = 32; s > 0; s >>= 1) {
    if (act && t < s) { red[t] += red[t + s]; red[64 + t] += red[64 + t + s]; }
    __syncthreads();
  }
  if (t == 0) { scal[b * 5 + 3] = red[0]; scal[b * 5 + 4] = red[64]; }
}

// ---------------- score from pair q rows: strided coalesced loads + wave reduce ----------------
__global__ __launch_bounds__(256) void k_score2(
    const ushort_t* __restrict__ q, const float4* __restrict__ pdat,
    const float* __restrict__ W1r, const float* __restrict__ b1r,
    const float* __restrict__ W2r, const float* __restrict__ dvec2,
    const float* __restrict__ b2r, float* __restrict__ out, int b0) {
  const int p = blockIdx.x;          // 0..2015
  const int bl = blockIdx.y;
  const int b = b0 + bl;
  const int t = threadIdx.x;
  float4 pd = pdat[(size_t)b * PROW + p];
  const int ij = __float_as_int(pd.w);
  const int i = ij >> 6, j = ij & 63;
  const float m = pd.z;
  const float a0ij = pd.x, a1ij = m - pd.x;
  const float a0ji = pd.y, a1ji = m - pd.y;
  const ushort_t* qp = q + ((size_t)bl * PROW + p) * QLD;
  float s1 = 0.f, s2 = 0.f;
  for (int n = t; n < 1540; n += 256) {
    float quv = bf2f(qp[n]) + dvec2[n];
    float base = fmaf(m, quv, b1r[n]);
    float w0 = W1r[n], w1 = W1r[1540 + n], w2 = W2r[n];
    float z1 = base + a0ij * w0 + a1ij * w1;
    float z2 = base + a0ji * w0 + a1ji * w1;
    s1 = fmaf(elu_f(z1), w2, s1);
    s2 = fmaf(elu_f(z2), w2, s2);
  }
#pragma unroll
  for (int mask = 1; mask < 64; mask <<= 1) {
    s1 += __shfl_xor(s1, mask, 64);
    s2 += __shfl_xor(s2, mask, 64);
  }
  __shared__ float r1[4], r2[4];
  if ((t & 63) == 0) { r1[t >> 6] = s1; r2[t >> 6] = s2; }
  __syncthreads();
  if (t == 0) {
    out[((size_t)b * 64 + i) * 64 + j] = r1[0] + r1[1] + r1[2] + r1[3] + b2r[0];
    out[((size_t)b * 64 + j) * 64 + i] = r2[0] + r2[1] + r2[2] + r2[3] + b2r[0];
  }
}

// ---------------- closed-form BN stats: ONE pass over UV ----------------
__global__ __launch_bounds__(256) void k_stats2(
    const float* __restrict__ UV, const float* __restrict__ W1t,
    const float* __restrict__ b1t,
    const float* __restrict__ r0s, const float* __restrict__ r1s,
    const float* __restrict__ c0s, const float* __restrict__ c1s,
    const float* __restrict__ scal,
    float* __restrict__ colsum, float* __restrict__ colss) {
  const int b = blockIdx.x;
  const int n = blockIdx.y * 256 + threadIdx.x;
  const int t = threadIdx.x;
  __shared__ float sr0[64], sr1[64], sc0[64], sc1[64];
  if (t < 64) {
    sr0[t] = r0s[b * 64 + t]; sr1[t] = r1s[b * 64 + t];
    sc0[t] = c0s[b * 64 + t]; sc1[t] = c1s[b * 64 + t];
  }
  __syncthreads();
  const float S0 = scal[b * 5], S1 = scal[b * 5 + 1], Q0 = scal[b * 5 + 2],
              Q1 = scal[b * 5 + 3], P = scal[b * 5 + 4];
  const float w0 = W1t[n], w1 = W1t[1536 + n], beta = b1t[n];
  float eU = 0, eV = 0, qU = 0, qV = 0, ur0 = 0, ur1 = 0, vc0 = 0, vc1 = 0;
  const float* base = UV + (size_t)b * 64 * 3072;
#pragma unroll 4
  for (int idx = 0; idx < 64; ++idx) {
    float U = base[(size_t)idx * 3072 + n];
    float V = base[(size_t)idx * 3072 + 1536 + n];
    eU += U; eV += V;
    qU = fmaf(U, U, qU); qV = fmaf(V, V, qV);
    ur0 = fmaf(U, sr0[idx], ur0); ur1 = fmaf(U, sr1[idx], ur1);
    vc0 = fmaf(V, sc0[idx], vc0); vc1 = fmaf(V, sc1[idx], vc1);
  }
  float hsum = 64.f * (eU + eV) + S0 * w0 + S1 * w1 + 4096.f * beta;
  float hss = 64.f * (qU + qV) + Q0 * w0 * w0 + Q1 * w1 * w1 + 4096.f * beta * beta
    + 2.f * (eU * eV + w0 * ur0 + w1 * ur1 + w0 * vc0 + w1 * vc1
             + 64.f * beta * (eU + eV) + w0 * w1 * P + beta * (w0 * S0 + w1 * S1));
  atomicAdd(&colsum[n], hsum);
  atomicAdd(&colss[n], hss);
}

// ---------------- finalize BN scale/shift ----------------
__global__ void k_bnfin(const float* __restrict__ colsum, const float* __restrict__ colss,
                        const float* __restrict__ gamma, const float* __restrict__ beta,
                        float* __restrict__ bns, float* __restrict__ bnt) {
  int n = blockIdx.x * 256 + threadIdx.x;
  if (n >= 1536) return;
  float mu = colsum[n] * (1.f / 65536.f);
  float var = colss[n] * (1.f / 65536.f) - mu * mu;
  float s = gamma[n] * rsqrtf(var + 1e-5f);
  bns[n] = s;
  bnt[n] = beta[n] - mu * s;
}

// ---------------- pair-summed hmid (fragment-tiled): one block per 16-pair group ----------------
// [539-proven ei-outer structure]
__global__ __launch_bounds__(256) void k_act4(
    const float* __restrict__ UV, const float4* __restrict__ pdat,
    const float* __restrict__ W1t, const float* __restrict__ b1t,
    const float* __restrict__ bns, const float* __restrict__ bnt,
    ushort_t* __restrict__ hmid_s, int b0) {
  const int g = blockIdx.x;            // chunk-local group
  const int b = b0 + (g >> 7);         // 128 groups per batch
  const int p0 = (g & 127) * 16;
  const int t = threadIdx.x;
  __shared__ __align__(16) ushort_t tile[KC * 128];   // 48 KB
  float w06[6], w16[6], s6[6], t6[6], bb6[6];
#pragma unroll
  for (int c = 0; c < 6; c++) {
    int n = t + 256 * c;
    w06[c] = W1t[n]; w16[c] = W1t[1536 + n];
    s6[c] = bns[n]; t6[c] = bnt[n]; bb6[c] = b1t[n];
  }
  const unsigned short zbf = 0;
  for (int ei = 0; ei < 16; ++ei) {
    const int p = p0 + ei;
    float4 pd = pdat[(size_t)b * PROW + p];
    int ij = __float_as_int(pd.w);
    if (ij >= 0) {
      int i = ij >> 6, j = ij & 63;
      const float* Ui = UV + (size_t)(b * 64 + i) * 3072;
      const float* Vi = Ui + 1536;
      const float* Uj = UV + (size_t)(b * 64 + j) * 3072;
      const float* Vj = Uj + 1536;
      float m = pd.z;
      float a0ij = pd.x, a1ij = m - pd.x;
      float a0ji = pd.y, a1ji = m - pd.y;
#pragma unroll
      for (int c = 0; c < 6; c++) {
        int n = t + 256 * c;
        float h1 = Ui[n] + Vj[n] + a0ij * w06[c] + a1ij * w16[c] + bb6[c];
        float h2 = Uj[n] + Vi[n] + a0ji * w06[c] + a1ji * w16[c] + bb6[c];
        float v = elu_f(fmaf(h1, s6[c], t6[c])) + elu_f(fmaf(h2, s6[c], t6[c]));
        int cc = n >> 3;
        int s = (ei + cc) & 15;
        tile[cc * 128 + s * 8 + (n & 7)] = f2bf(v);
      }
    } else {
#pragma unroll
      for (int c = 0; c < 6; c++) {
        int n = t + 256 * c;
        int cc = n >> 3;
        int s = (ei + cc) & 15;
        tile[cc * 128 + s * 8 + (n & 7)] = zbf;
      }
    }
  }
  __syncthreads();
  uint4* gout = (uint4*)(hmid_s + (size_t)g * (KC * 128));
  const uint4* lt = (const uint4*)tile;
#pragma unroll
  for (int it = 0; it < 12; ++it) {          // 3072 16B units
    int u = t + 256 * it;
    int cc = u >> 4, r = u & 15;
    gout[u] = lt[cc * 16 + ((r + cc) & 15)];
  }
}

extern "C" void kernel_launch(void* const* d_in, const int* in_sizes, int n_in,
                              void* d_out, int out_size, void* d_ws, size_t ws_size,
                              hipStream_t stream) {
  const float* x     = (const float*)d_in[0];
  const float* adjs  = (const float*)d_in[1];
  const float* flags = (const float*)d_in[2];
  const float* Wg    = (const float*)d_in[3];
  const float* bg    = (const float*)d_in[4];
  const float* Wout  = (const float*)d_in[5];
  const float* bout  = (const float*)d_in[6];
  const float* W1t   = (const float*)d_in[7];
  const float* b1t   = (const float*)d_in[8];
  const float* gamma = (const float*)d_in[9];
  const float* beta  = (const float*)d_in[10];
  const float* W2t   = (const float*)d_in[11];
  const float* b2t   = (const float*)d_in[12];
  const float* W1r   = (const float*)d_in[13];
  const float* b1r   = (const float*)d_in[14];
  const float* W2r   = (const float*)d_in[15];
  const float* b2r   = (const float*)d_in[16];
  float* out_score = (float*)d_out;
  float* out_xo    = (float*)d_out + 65536;

  uint8_t* ws = (uint8_t*)d_ws;
  size_t off = 0;
  auto alloc = [&](size_t bytes) -> void* {
    void* p = ws + off;
    off += (bytes + 255) & ~(size_t)255;
    return p;
  };
  float*    h0      = (float*)   alloc((size_t)1024 * 256 * 4);
  float*    concat  = (float*)   alloc((size_t)1024 * 384 * 4);
  ushort_t* xo_bf   = (ushort_t*)alloc((size_t)1024 * 768 * 2);
  ushort_t* W1tT    = (ushort_t*)alloc((size_t)3072 * 768 * 2);
  ushort_t* W2t_bf  = (ushort_t*)alloc((size_t)1536 * 768 * 2);
  ushort_t* WrxT    = (ushort_t*)alloc((size_t)NQPAD * 768 * 2);
  ushort_t* WcT     = (ushort_t*)alloc((size_t)NQPAD * 1536 * 2);  // fragment-tiled
  float*    UV      = (float*)   alloc((size_t)1024 * 3072 * 4);
  float*    dvec2   = (float*)   alloc((size_t)1664 * 4);   // contiguous with colsum/colss
  float*    colsum  = (float*)   alloc((size_t)1536 * 4);
  float*    colss   = (float*)   alloc((size_t)1536 * 4);
  float*    bns     = (float*)   alloc((size_t)1536 * 4);
  float*    bnt     = (float*)   alloc((size_t)1536 * 4);
  float*    r0s     = (float*)   alloc((size_t)1024 * 4);
  float*    r1s     = (float*)   alloc((size_t)1024 * 4);
  float*    c0s     = (float*)   alloc((size_t)1024 * 4);
  float*    c1s     = (float*)   alloc((size_t)1024 * 4);
  float*    scal    = (float*)   alloc((size_t)80 * 4);
  float4*   pdat    = (float4*)  alloc((size_t)16 * PROW * 16);

  // Adaptive chunk size (batches per chunk): hmid_s + q buffers must fit
  int cb = 2;
  {
    const int cands[4] = {16, 8, 4, 2};
    for (int ci = 0; ci < 4; ++ci) {
      int c = cands[ci];
      size_t need = off + ((size_t)c * PROW * 1536 * 2 + 256)
                        + ((size_t)c * PROW * QLD * 2 + 256);
      if (need <= ws_size) { cb = c; break; }
    }
  }
  ushort_t* hmid_s  = (ushort_t*)alloc((size_t)cb * PROW * 1536 * 2);   // fragment-tiled
  ushort_t* q_c     = (ushort_t*)alloc((size_t)cb * PROW * QLD * 2);    // row-major
  (void)in_sizes; (void)n_in; (void)out_size;

  // init accumulators + score diagonal (ws/out re-poisoned every launch)
  k_prep<<<dim3(19), dim3(256), 0, stream>>>(dvec2, 1664 + 1536 + 1536, out_score);

  // GIN chain (fp32 — x_o is a direct output)
  k_agg<<<dim3(1024), dim3(128), 0, stream>>>(x, adjs, flags, h0, concat);
  k_sgemm<<<dim3(4, 16), dim3(256), 0, stream>>>(h0, Wg, concat + 128, (ushort_t*)nullptr,
                                                 bg, flags, 256, 256, 256, 384, 1);
  k_sgemm<<<dim3(12, 16), dim3(256), 0, stream>>>(concat, Wout, out_xo, xo_bf,
                                                  bout, flags, 384, 384, 768, 768, 2);

  // merged weight prep (transposes + cast + dvec) + adjacency moments + pair data
  k_wprep<<<dim3(52, 24, 5), dim3(32, 8), 0, stream>>>(W1t, W1r, W2t, b2t,
                                                       W1tT, WrxT, W2t_bf, dvec2);
  k_adjpdat<<<dim3(16, 9), dim3(256), 0, stream>>>(adjs, flags, r0s, r1s, c0s, c1s,
                                                   scal, pdat);

  // UV = x_o @ [W1t_i | W1t_j]   (fp32 out, row-major)
  k_gemm<<<dim3(24, 8), dim3(256), 0, stream>>>(xo_bf, W1tT, UV, (ushort_t*)nullptr,
                                                768, 768, 768, 3072, 3072, 0);
  // WcT = (W2t @ W1r[2:770])^T  -> fragment-tiled bf16
  k_gemm<<<dim3(12, 13), dim3(256), 0, stream>>>(WrxT, W2t_bf, (float*)nullptr, WcT,
                                                 768, 768, 768, 1536, 1536, 1);

  // closed-form BN stats (single UV pass), finalize
  k_stats2<<<dim3(16, 6), dim3(256), 0, stream>>>(UV, W1t, b1t, r0s, r1s, c0s, c1s, scal,
                                                  colsum, colss);
  k_bnfin<<<dim3(6), dim3(256), 0, stream>>>(colsum, colss, gamma, beta, bns, bnt);

  // heavy pipeline: pair-summed act -> pure GEMM (q bf16) -> pair score
  for (int b0 = 0; b0 < 16; b0 += cb) {
    k_act4<<<dim3(cb * 128), dim3(256), 0, stream>>>(UV, pdat, W1t, b1t, bns, bnt,
                                                     hmid_s, b0);
    k_gemm_t<<<dim3(13, cb * 16), dim3(256), 0, stream>>>(hmid_s, WcT, q_c,
                                                          QLD, 1540, 1);
    k_score2<<<dim3(NPAIR, cb), dim3(256), 0, stream>>>(q_c, pdat, W1r, b1r, W2r,
                                                        dvec2, b2r, out_score, b0);
  }
}